// Round 6
// baseline (542.748 us; speedup 1.0000x reference)
//
#include <hip/hip_runtime.h>

#define Bq 2
#define Lq 1024
#define Dq 1024
#define Hq 16
#define HDq 64
#define HIDq 4096
#define Mq (Bq*Lq)   // 2048

typedef __bf16 bf16x8 __attribute__((ext_vector_type(8)));
typedef float floatx4 __attribute__((ext_vector_type(4)));

__device__ __forceinline__ unsigned short f2us(float f){
  unsigned u = __builtin_bit_cast(unsigned, f);
  u = u + 0x7fffu + ((u >> 16) & 1u);      // RNE to bf16
  return (unsigned short)(u >> 16);
}

// async global->LDS, 16B per lane (dest must be linear: wave base + lane*16)
__device__ __forceinline__ void gld16(const unsigned short* g, unsigned short* l){
  __builtin_amdgcn_global_load_lds(
      (const __attribute__((address_space(1))) unsigned int*)g,
      (__attribute__((address_space(3))) unsigned int*)l, 16, 0, 0);
}

// ---------------- f32 -> bf16 conversion (weights), 4 arrays per launch ----------------
__global__ __launch_bounds__(256) void cvt4_kernel(
    const float* __restrict__ s0, const float* __restrict__ s1,
    const float* __restrict__ s2, const float* __restrict__ s3,
    unsigned short* __restrict__ d0, unsigned short* __restrict__ d1,
    unsigned short* __restrict__ d2, unsigned short* __restrict__ d3,
    int n)
{
  const int a = blockIdx.y;
  const float* s = (a==0) ? s0 : (a==1) ? s1 : (a==2) ? s2 : s3;
  unsigned short* d = (a==0) ? d0 : (a==1) ? d1 : (a==2) ? d2 : d3;
  const int i = (blockIdx.x * 256 + threadIdx.x) * 8;
  if (i >= n) return;
  float4 v0 = ((const float4*)(s + i))[0];
  float4 v1 = ((const float4*)(s + i))[1];
  ushort4 o0, o1;
  o0.x=f2us(v0.x); o0.y=f2us(v0.y); o0.z=f2us(v0.z); o0.w=f2us(v0.w);
  o1.x=f2us(v1.x); o1.y=f2us(v1.y); o1.z=f2us(v1.z); o1.w=f2us(v1.w);
  ((ushort4*)(d + i))[0] = o0;
  ((ushort4*)(d + i))[1] = o1;
}

// ---------------- complex LayerNorm: f32 in, bf16 out; one block per row ----------------
__global__ __launch_bounds__(256) void cln_kernel(
    const float* __restrict__ xr, const float* __restrict__ xi,
    const float* __restrict__ gr, const float* __restrict__ gi,
    const float* __restrict__ br, const float* __restrict__ bi,
    unsigned short* __restrict__ outr, unsigned short* __restrict__ outi)
{
  const int row = blockIdx.x;
  const int t = threadIdx.x;
  const int lane = t & 63, wv = t >> 6;
  __shared__ float sred[8];

  float4 v4r = ((const float4*)(xr + (size_t)row*Dq))[t];
  float4 v4i = ((const float4*)(xi + (size_t)row*Dq))[t];
  float vr[4] = {v4r.x, v4r.y, v4r.z, v4r.w};
  float vi[4] = {v4i.x, v4i.y, v4i.z, v4i.w};
  float sr = vr[0]+vr[1]+vr[2]+vr[3];
  float si = vi[0]+vi[1]+vi[2]+vi[3];
  #pragma unroll
  for (int o=32;o>0;o>>=1){ sr += __shfl_down(sr,o,64); si += __shfl_down(si,o,64); }
  if (lane==0){ sred[wv]=sr; sred[4+wv]=si; }
  __syncthreads();
  float mr = (sred[0]+sred[1]+sred[2]+sred[3]) * (1.0f/Dq);
  float mi = (sred[4]+sred[5]+sred[6]+sred[7]) * (1.0f/Dq);
  float cr[4], ci[4], vs = 0.f;
  #pragma unroll
  for (int j=0;j<4;++j){ cr[j]=vr[j]-mr; ci[j]=vi[j]-mi; vs += cr[j]*cr[j]+ci[j]*ci[j]; }
  #pragma unroll
  for (int o=32;o>0;o>>=1) vs += __shfl_down(vs,o,64);
  __syncthreads();
  if (lane==0) sred[wv]=vs;
  __syncthreads();
  float var = (sred[0]+sred[1]+sred[2]+sred[3]) * (1.0f/Dq);
  float inv = rsqrtf(var + 1e-6f);

  float4 g4r = ((const float4*)gr)[t];
  float4 g4i = ((const float4*)gi)[t];
  float4 b4r = ((const float4*)br)[t];
  float4 b4i = ((const float4*)bi)[t];
  float grf[4] = {g4r.x,g4r.y,g4r.z,g4r.w};
  float gif[4] = {g4i.x,g4i.y,g4i.z,g4i.w};
  float brf[4] = {b4r.x,b4r.y,b4r.z,b4r.w};
  float bif[4] = {b4i.x,b4i.y,b4i.z,b4i.w};
  ushort4 o_r, o_i;
  unsigned short orr[4], oii[4];
  #pragma unroll
  for (int j=0;j<4;++j){
    float nr = cr[j]*inv, ni = ci[j]*inv;
    orr[j] = f2us(nr*grf[j] - ni*gif[j] + brf[j]);
    oii[j] = f2us(nr*gif[j] + ni*grf[j] + bif[j]);
  }
  o_r.x=orr[0]; o_r.y=orr[1]; o_r.z=orr[2]; o_r.w=orr[3];
  o_i.x=oii[0]; o_i.y=oii[1]; o_i.z=oii[2]; o_i.w=oii[3];
  ((ushort4*)(outr + (size_t)row*Dq))[t] = o_r;
  ((ushort4*)(outi + (size_t)row*Dq))[t] = o_i;
}

// ---------------- complex GEMM: C = A @ W^T, MFMA 16x16x32, dbuf + global_load_lds ----------------
// Block: 256 threads (4 waves, 2x2). Tile 64(M) x 64(N), BK=32, double-buffered LDS (32 KB).
// EPI: 0 plain bf16; 1 +bias+resid(f32)->f32; 2 +bias+ModReLU->bf16; 3 = 1;
//      4 raw f32 partial (split-K: blockIdx.z selects K-chunk and partial buffer).
// SPLIT3: output scattered to 3 arrays of stride 1024 by n0>>10 (merged QKV).
template<int EPI, bool ROPE, bool SPLIT3, int SPLITK>
__global__ __launch_bounds__(256,3) void cgemm16_kernel(
    const unsigned short* __restrict__ Ar, const unsigned short* __restrict__ Ai,
    const unsigned short* __restrict__ Wr, const unsigned short* __restrict__ Wi,
    void* __restrict__ Cr0, void* __restrict__ Ci0,
    void* __restrict__ Cr1, void* __restrict__ Ci1,
    void* __restrict__ Cr2, void* __restrict__ Ci2,
    const float* __restrict__ biasR, const float* __restrict__ biasI,
    const float* __restrict__ resR, const float* __restrict__ resI,
    const float* __restrict__ modb,
    int Ndim, int Kdim)
{
  const int t = threadIdx.x;
  const int w = t >> 6, lane = t & 63;
  const int quad = lane >> 4, l15 = lane & 15;
  const int wr = w >> 1, wc = w & 1;
  const int m0 = blockIdx.x * 64, n0 = blockIdx.y * 64;
  const int kbase = (SPLITK > 1) ? (int)blockIdx.z * (Kdim / SPLITK) : 0;
  const int Klen = Kdim / SPLITK;

  __shared__ __align__(16) unsigned short sAr0[64*32], sAi0[64*32], sWr0[64*32], sWi0[64*32];
  __shared__ __align__(16) unsigned short sAr1[64*32], sAi1[64*32], sWr1[64*32], sWi1[64*32];

  const floatx4 fz = {0.f,0.f,0.f,0.f};
  floatx4 accRR[2][2], accII[2][2], accRI[2][2], accIR[2][2];
  #pragma unroll
  for (int i=0;i<2;++i)
    #pragma unroll
    for (int j=0;j<2;++j){ accRR[i][j]=fz; accII[i][j]=fz; accRI[i][j]=fz; accIR[i][j]=fz; }

  // ---- staging: thread t -> LDS slot t (row t>>2, chunk t&3); logical chunk = (t&3)^((t>>2)&3)
  const int srow = t >> 2;
  const int lc = ((t & 3) ^ ((t >> 2) & 3)) * 8;     // ushort offset within row
  const unsigned short* pAr = Ar + (size_t)(m0 + srow)*Kdim + lc + kbase;
  const unsigned short* pAi = Ai + (size_t)(m0 + srow)*Kdim + lc + kbase;
  const unsigned short* pWr = Wr + (size_t)(n0 + srow)*Kdim + lc + kbase;
  const unsigned short* pWi = Wi + (size_t)(n0 + srow)*Kdim + lc + kbase;
  const int dst0 = t * 8;

  // ---- fragment read offsets (ushort idx): row*32 + (quad ^ (row&3))*8
  const int arow0 = wr*32 + l15,       arow1 = arow0 + 16;
  const int wrow0 = wc*16 + l15,       wrow1 = wrow0 + 32;
  const int aoff0 = arow0*32 + ((quad ^ (arow0 & 3))*8);
  const int aoff1 = arow1*32 + ((quad ^ (arow1 & 3))*8);
  const int woff0 = wrow0*32 + ((quad ^ (wrow0 & 3))*8);
  const int woff1 = wrow1*32 + ((quad ^ (wrow1 & 3))*8);

#define STAGEK(SA, SB, SC, SD, KOFF) do{                                   \
    gld16(pAr + (KOFF), &SA[dst0]);                                        \
    gld16(pAi + (KOFF), &SB[dst0]);                                        \
    gld16(pWr + (KOFF), &SC[dst0]);                                        \
    gld16(pWi + (KOFF), &SD[dst0]);                                        \
  }while(0)

#define COMPUTEK(SA, SB, SC, SD) do{                                       \
    bf16x8 fA0r = *(const bf16x8*)&SA[aoff0];                              \
    bf16x8 fA1r = *(const bf16x8*)&SA[aoff1];                              \
    bf16x8 fA0i = *(const bf16x8*)&SB[aoff0];                              \
    bf16x8 fA1i = *(const bf16x8*)&SB[aoff1];                              \
    bf16x8 fW0r = *(const bf16x8*)&SC[woff0];                              \
    bf16x8 fW1r = *(const bf16x8*)&SC[woff1];                              \
    bf16x8 fW0i = *(const bf16x8*)&SD[woff0];                              \
    bf16x8 fW1i = *(const bf16x8*)&SD[woff1];                              \
    accRR[0][0] = __builtin_amdgcn_mfma_f32_16x16x32_bf16(fA0r, fW0r, accRR[0][0], 0,0,0); \
    accII[0][0] = __builtin_amdgcn_mfma_f32_16x16x32_bf16(fA0i, fW0i, accII[0][0], 0,0,0); \
    accRI[0][0] = __builtin_amdgcn_mfma_f32_16x16x32_bf16(fA0r, fW0i, accRI[0][0], 0,0,0); \
    accIR[0][0] = __builtin_amdgcn_mfma_f32_16x16x32_bf16(fA0i, fW0r, accIR[0][0], 0,0,0); \
    accRR[0][1] = __builtin_amdgcn_mfma_f32_16x16x32_bf16(fA0r, fW1r, accRR[0][1], 0,0,0); \
    accII[0][1] = __builtin_amdgcn_mfma_f32_16x16x32_bf16(fA0i, fW1i, accII[0][1], 0,0,0); \
    accRI[0][1] = __builtin_amdgcn_mfma_f32_16x16x32_bf16(fA0r, fW1i, accRI[0][1], 0,0,0); \
    accIR[0][1] = __builtin_amdgcn_mfma_f32_16x16x32_bf16(fA0i, fW1r, accIR[0][1], 0,0,0); \
    accRR[1][0] = __builtin_amdgcn_mfma_f32_16x16x32_bf16(fA1r, fW0r, accRR[1][0], 0,0,0); \
    accII[1][0] = __builtin_amdgcn_mfma_f32_16x16x32_bf16(fA1i, fW0i, accII[1][0], 0,0,0); \
    accRI[1][0] = __builtin_amdgcn_mfma_f32_16x16x32_bf16(fA1r, fW0i, accRI[1][0], 0,0,0); \
    accIR[1][0] = __builtin_amdgcn_mfma_f32_16x16x32_bf16(fA1i, fW0r, accIR[1][0], 0,0,0); \
    accRR[1][1] = __builtin_amdgcn_mfma_f32_16x16x32_bf16(fA1r, fW1r, accRR[1][1], 0,0,0); \
    accII[1][1] = __builtin_amdgcn_mfma_f32_16x16x32_bf16(fA1i, fW1i, accII[1][1], 0,0,0); \
    accRI[1][1] = __builtin_amdgcn_mfma_f32_16x16x32_bf16(fA1r, fW1i, accRI[1][1], 0,0,0); \
    accIR[1][1] = __builtin_amdgcn_mfma_f32_16x16x32_bf16(fA1i, fW1r, accIR[1][1], 0,0,0); \
  }while(0)

  const int nk = Klen >> 5;          // always even here (16/32/64/96)
  STAGEK(sAr0, sAi0, sWr0, sWi0, 0);
  __syncthreads();
  for (int kk=0; kk<nk; kk+=2){
    STAGEK(sAr1, sAi1, sWr1, sWi1, (size_t)(kk+1)*32);
    COMPUTEK(sAr0, sAi0, sWr0, sWi0);
    __syncthreads();                              // drains stage(buf1); frees buf0
    if (kk+2 < nk) STAGEK(sAr0, sAi0, sWr0, sWi0, (size_t)(kk+2)*32);
    COMPUTEK(sAr1, sAi1, sWr1, sWi1);
    __syncthreads();                              // drains stage(buf0); frees buf1
  }
#undef STAGEK
#undef COMPUTEK

  // ---- epilogue: C 16x16 layout: col = l15, row = quad*4 + r ----
  float cr[2][2][4], ci[2][2][4];
  #pragma unroll
  for (int mf=0; mf<2; ++mf)
    #pragma unroll
    for (int nf=0; nf<2; ++nf)
      #pragma unroll
      for (int r=0;r<4;++r){
        cr[mf][nf][r] = accRR[mf][nf][r] - accII[mf][nf][r];
        ci[mf][nf][r] = accRI[mf][nf][r] + accIR[mf][nf][r];
      }

  // RoPE: head = this 64-col block; d = wc*16 + nfi*32 + l15, pair (d, d+32) = (nf0, nf1)
  const bool doRope = ROPE && (!SPLIT3 || (n0 < 2048));
  if (doRope){
    const float invf = powf(10000.0f, -(float)(wc*16 + l15) * (1.0f/32.0f));
    #pragma unroll
    for (int mf=0; mf<2; ++mf)
      #pragma unroll
      for (int r=0;r<4;++r){
        const int gm = m0 + wr*32 + mf*16 + quad*4 + r;
        float s, c;
        sincosf((float)(gm & (Lq-1)) * invf, &s, &c);
        float xr_ = cr[mf][0][r], yr_ = cr[mf][1][r];
        cr[mf][0][r] = xr_*c - yr_*s;  cr[mf][1][r] = yr_*c + xr_*s;
        float xi_ = ci[mf][0][r], yi_ = ci[mf][1][r];
        ci[mf][0][r] = xi_*c - yi_*s;  ci[mf][1][r] = yi_*c + xi_*s;
      }
  }

  unsigned short *oR16 = nullptr, *oI16 = nullptr;
  float *oR32 = nullptr, *oI32 = nullptr;
  int ncol0, Nst;
  if (SPLIT3){
    const int aid = n0 >> 10;
    void* vr = (aid==0) ? Cr0 : ((aid==1) ? Cr1 : Cr2);
    void* vi = (aid==0) ? Ci0 : ((aid==1) ? Ci1 : Ci2);
    oR16 = (unsigned short*)vr; oI16 = (unsigned short*)vi;
    ncol0 = n0 & 1023; Nst = 1024;
  } else {
    oR16 = (unsigned short*)Cr0; oI16 = (unsigned short*)Ci0;
    oR32 = (float*)Cr0;          oI32 = (float*)Ci0;
    ncol0 = n0; Nst = Ndim;
  }
  if (EPI == 4){
    const size_t pstride = (size_t)Mq * Ndim;
    oR32 = (float*)Cr0 + (size_t)blockIdx.z * pstride;
    oI32 = (float*)Ci0 + (size_t)blockIdx.z * pstride;
  }

  #pragma unroll
  for (int nf=0; nf<2; ++nf){
    const int gn = n0 + wc*16 + nf*32 + l15;      // full-N index (bias/modb)
    const int cn = ncol0 + wc*16 + nf*32 + l15;   // output-array col
    float bR = 0.f, bI = 0.f, mb = 0.f;
    if (EPI >= 1 && EPI <= 3){ bR = biasR[gn]; bI = biasI[gn]; }
    if (EPI == 2){ mb = modb[gn]; }
    #pragma unroll
    for (int mf=0; mf<2; ++mf)
      #pragma unroll
      for (int r=0;r<4;++r){
        const int gm = m0 + wr*32 + mf*16 + quad*4 + r;
        const size_t idx = (size_t)gm*Nst + cn;
        float vr_ = cr[mf][nf][r] + bR, vi_ = ci[mf][nf][r] + bI;
        if (EPI == 1 || EPI == 3){ vr_ += resR[idx]; vi_ += resI[idx]; }
        if (EPI == 2){
          float mag = sqrtf(vr_*vr_ + vi_*vi_);
          float safe = (mag > 0.f) ? mag : 1.0f;
          float act = fmaxf(mag + mb, 0.f);
          float sc = act / safe;
          vr_ *= sc; vi_ *= sc;
        }
        if (EPI == 0 || EPI == 2){
          oR16[idx] = f2us(vr_);
          oI16[idx] = f2us(vi_);
        } else {
          oR32[idx] = vr_;
          oI32[idx] = vi_;
        }
      }
  }
}

// ---------------- split-K reduce: out = sum(partials) + bias + resid (f32) ----------------
template<int NS>
__global__ __launch_bounds__(256) void redk_kernel(
    const float* __restrict__ pR, const float* __restrict__ pI,
    const float* __restrict__ bR, const float* __restrict__ bI,
    const float* __restrict__ rR, const float* __restrict__ rI,
    float* __restrict__ oR, float* __restrict__ oI)
{
  const size_t MN = (size_t)Mq * Dq;
  const size_t i = ((size_t)blockIdx.x * 256 + threadIdx.x) * 4;
  const int col = (int)(i & (Dq - 1));
  float4 br = *(const float4*)(bR + col);
  float4 bi = *(const float4*)(bI + col);
  float4 xr = *(const float4*)(rR + i);
  float4 xi = *(const float4*)(rI + i);
  float ar0 = br.x + xr.x, ar1 = br.y + xr.y, ar2 = br.z + xr.z, ar3 = br.w + xr.w;
  float ai0 = bi.x + xi.x, ai1 = bi.y + xi.y, ai2 = bi.z + xi.z, ai3 = bi.w + xi.w;
  #pragma unroll
  for (int s=0; s<NS; ++s){
    float4 qr = *(const float4*)(pR + s*MN + i);
    float4 qi = *(const float4*)(pI + s*MN + i);
    ar0 += qr.x; ar1 += qr.y; ar2 += qr.z; ar3 += qr.w;
    ai0 += qi.x; ai1 += qi.y; ai2 += qi.z; ai3 += qi.w;
  }
  float4 orv = {ar0, ar1, ar2, ar3};
  float4 oiv = {ai0, ai1, ai2, ai3};
  *(float4*)(oR + i) = orv;
  *(float4*)(oI + i) = oiv;
}

// ---------------- V transpose: V[b,l,h*64+d] -> VT[(b*16+h)*64+d][l] ----------------
__global__ __launch_bounds__(256) void vtrans_kernel(
    const unsigned short* __restrict__ Vr, const unsigned short* __restrict__ Vi,
    unsigned short* __restrict__ VTr, unsigned short* __restrict__ VTi)
{
  const int lt = blockIdx.x;      // 0..15 (L tile)
  const int bh = blockIdx.y;      // 0..31
  const int h = bh & (Hq-1), b = bh >> 4;
  const int t = threadIdx.x;
  __shared__ unsigned short sTr[64*65], sTi[64*65];

  const int row = t >> 2;          // l-local 0..63
  const int dc  = (t & 3) * 16;    // d chunk
  const size_t g = ((size_t)(b*Lq) + lt*64 + row)*Dq + h*HDq + dc;
  uint4 a0 = *(const uint4*)(Vr + g);
  uint4 a1 = *(const uint4*)(Vr + g + 8);
  uint4 b0 = *(const uint4*)(Vi + g);
  uint4 b1 = *(const uint4*)(Vi + g + 8);
  const unsigned short* pa0 = (const unsigned short*)&a0;
  const unsigned short* pa1 = (const unsigned short*)&a1;
  const unsigned short* pb0 = (const unsigned short*)&b0;
  const unsigned short* pb1 = (const unsigned short*)&b1;
  #pragma unroll
  for (int e=0;e<8;++e){
    sTr[(dc+e)*65 + row]   = pa0[e];
    sTr[(dc+8+e)*65 + row] = pa1[e];
    sTi[(dc+e)*65 + row]   = pb0[e];
    sTi[(dc+8+e)*65 + row] = pb1[e];
  }
  __syncthreads();
  const int d  = t >> 2;
  const int lcx = (t & 3) * 16;
  unsigned short bufr[16], bufi[16];
  #pragma unroll
  for (int e=0;e<16;++e){
    bufr[e] = sTr[d*65 + lcx + e];
    bufi[e] = sTi[d*65 + lcx + e];
  }
  const size_t og = ((size_t)bh*HDq + d)*Lq + lt*64 + lcx;
  *(uint4*)(VTr + og)     = *(const uint4*)&bufr[0];
  *(uint4*)(VTr + og + 8) = *(const uint4*)&bufr[8];
  *(uint4*)(VTi + og)     = *(const uint4*)&bufi[0];
  *(uint4*)(VTi + og + 8) = *(const uint4*)&bufi[8];
}

// ---------------- flash attention: 64x64 tiles, MFMA, online softmax ----------------
__device__ __forceinline__ int swz(int v){ return v ^ ((v >> 4) & 7); }

__global__ __launch_bounds__(256,2) void fattn_kernel(
    const unsigned short* __restrict__ Qr, const unsigned short* __restrict__ Qi,
    const unsigned short* __restrict__ Kr, const unsigned short* __restrict__ Ki,
    const unsigned short* __restrict__ VTr, const unsigned short* __restrict__ VTi,
    unsigned short* __restrict__ Or, unsigned short* __restrict__ Oi)
{
  const int qt = (int)(gridDim.x - 1 - blockIdx.x);   // big tiles dispatch first
  const int bh = blockIdx.y;
  const int h = bh & (Hq-1), b = bh >> 4;
  const int t = threadIdx.x;
  const int w = t >> 6, lane = t & 63;
  const int quad = lane >> 4, l15 = lane & 15;

  __shared__ __align__(16) unsigned short sKr[4096], sKi[4096], sVr[4096], sVi[4096];
  __shared__ __align__(16) unsigned short sP[64*72];

  const size_t qbase = ((size_t)(b*Lq) + qt*64 + w*16 + l15)*Dq + h*HDq;
  bf16x8 qr_lo = *(const bf16x8*)(Qr + qbase + quad*8);
  bf16x8 qr_hi = *(const bf16x8*)(Qr + qbase + 32 + quad*8);
  bf16x8 qi_lo = *(const bf16x8*)(Qi + qbase + quad*8);
  bf16x8 qi_hi = *(const bf16x8*)(Qi + qbase + 32 + quad*8);

  const floatx4 fzero = {0.f,0.f,0.f,0.f};
  floatx4 aOr[4], aOi[4];
  #pragma unroll
  for (int i=0;i<4;++i){ aOr[i]=fzero; aOi[i]=fzero; }
  float m_run[4] = {-1e30f,-1e30f,-1e30f,-1e30f};
  float l_run[4] = {0.f,0.f,0.f,0.f};

  const int srow = t >> 2;
  const int sns  = srow >> 4;
  const int sl15 = srow & 15;
  const int q8   = (t & 3) * 2;
  const int dstA = sns*1024 + swz(q8*16 + sl15)*8;
  const int dstB = sns*1024 + swz((q8+1)*16 + sl15)*8;

  const int rd0 = swz(quad*16 + l15)*8;
  const int rd1 = swz((4+quad)*16 + l15)*8;

  for (int kt = 0; kt <= qt; ++kt){
    const size_t kg = ((size_t)(b*Lq) + kt*64 + srow)*Dq + h*HDq + q8*8;
    uint4 ka = *(const uint4*)(Kr + kg);
    uint4 kb = *(const uint4*)(Kr + kg + 8);
    uint4 kc = *(const uint4*)(Ki + kg);
    uint4 kd = *(const uint4*)(Ki + kg + 8);
    const size_t vg = ((size_t)bh*HDq + srow)*Lq + kt*64 + q8*8;
    uint4 va = *(const uint4*)(VTr + vg);
    uint4 vb = *(const uint4*)(VTr + vg + 8);
    uint4 vc = *(const uint4*)(VTi + vg);
    uint4 vd = *(const uint4*)(VTi + vg + 8);
    __syncthreads();
    *(uint4*)&sKr[dstA] = ka;  *(uint4*)&sKr[dstB] = kb;
    *(uint4*)&sKi[dstA] = kc;  *(uint4*)&sKi[dstB] = kd;
    *(uint4*)&sVr[dstA] = va;  *(uint4*)&sVr[dstB] = vb;
    *(uint4*)&sVi[dstA] = vc;  *(uint4*)&sVi[dstB] = vd;
    __syncthreads();

    floatx4 sc[4];
    #pragma unroll
    for (int ns=0; ns<4; ++ns){
      floatx4 x = fzero;
      x = __builtin_amdgcn_mfma_f32_16x16x32_bf16(qr_lo, *(const bf16x8*)&sKr[ns*1024 + rd0], x, 0,0,0);
      x = __builtin_amdgcn_mfma_f32_16x16x32_bf16(qr_hi, *(const bf16x8*)&sKr[ns*1024 + rd1], x, 0,0,0);
      x = __builtin_amdgcn_mfma_f32_16x16x32_bf16(qi_lo, *(const bf16x8*)&sKi[ns*1024 + rd0], x, 0,0,0);
      x = __builtin_amdgcn_mfma_f32_16x16x32_bf16(qi_hi, *(const bf16x8*)&sKi[ns*1024 + rd1], x, 0,0,0);
      sc[ns] = x;
    }

    const bool diag = (kt == qt);
    float rmax[4] = {-1e30f,-1e30f,-1e30f,-1e30f};
    #pragma unroll
    for (int ns=0; ns<4; ++ns){
      #pragma unroll
      for (int r=0; r<4; ++r){
        float s = sc[ns][r] * 0.125f;
        if (diag && (ns*16 + l15 > w*16 + quad*4 + r)) s = -1e30f;
        sc[ns][r] = s;
        rmax[r] = fmaxf(rmax[r], s);
      }
    }
    #pragma unroll
    for (int off=1; off<16; off<<=1){
      #pragma unroll
      for (int r=0; r<4; ++r) rmax[r] = fmaxf(rmax[r], __shfl_xor(rmax[r], off, 64));
    }

    float alpha[4], rsum[4];
    #pragma unroll
    for (int r=0; r<4; ++r){
      float mn = fmaxf(m_run[r], rmax[r]);
      alpha[r] = __expf(m_run[r] - mn);
      m_run[r] = mn;
      rsum[r] = 0.f;
    }
    #pragma unroll
    for (int ns=0; ns<4; ++ns){
      #pragma unroll
      for (int r=0; r<4; ++r){
        float p = __expf(sc[ns][r] - m_run[r]);
        rsum[r] += p;
        sP[(w*16 + quad*4 + r)*72 + ns*16 + l15] = f2us(p);
      }
    }
    #pragma unroll
    for (int off=1; off<16; off<<=1){
      #pragma unroll
      for (int r=0; r<4; ++r) rsum[r] += __shfl_xor(rsum[r], off, 64);
    }
    #pragma unroll
    for (int r=0; r<4; ++r) l_run[r] = l_run[r]*alpha[r] + rsum[r];
    #pragma unroll
    for (int ds=0; ds<4; ++ds)
      #pragma unroll
      for (int r=0; r<4; ++r){ aOr[ds][r] *= alpha[r]; aOi[ds][r] *= alpha[r]; }

    #pragma unroll
    for (int step=0; step<2; ++step){
      bf16x8 pf = *(const bf16x8*)&sP[(w*16 + l15)*72 + step*32 + quad*8];
      const int ro = (step==0) ? rd0 : rd1;
      #pragma unroll
      for (int ds=0; ds<4; ++ds){
        aOr[ds] = __builtin_amdgcn_mfma_f32_16x16x32_bf16(pf, *(const bf16x8*)&sVr[ds*1024 + ro], aOr[ds], 0,0,0);
        aOi[ds] = __builtin_amdgcn_mfma_f32_16x16x32_bf16(pf, *(const bf16x8*)&sVi[ds*1024 + ro], aOi[ds], 0,0,0);
      }
    }
  }

  #pragma unroll
  for (int r=0; r<4; ++r){
    const float il = 1.0f / l_run[r];
    const size_t ob = ((size_t)(b*Lq) + qt*64 + w*16 + quad*4 + r)*Dq + h*HDq;
    #pragma unroll
    for (int ds=0; ds<4; ++ds){
      Or[ob + ds*16 + l15] = f2us(aOr[ds][r] * il);
      Oi[ob + ds*16 + l15] = f2us(aOi[ds][r] * il);
    }
  }
}

// ---------------- launch ----------------
extern "C" void kernel_launch(void* const* d_in, const int* in_sizes, int n_in,
                              void* d_out, int out_size, void* d_ws, size_t ws_size,
                              hipStream_t stream)
{
  const float* x_r    = (const float*)d_in[0];
  const float* x_i    = (const float*)d_in[1];
  const float* Wq_r   = (const float*)d_in[2];
  const float* Wq_i   = (const float*)d_in[3];
  const float* Wk_r   = (const float*)d_in[4];
  const float* Wk_i   = (const float*)d_in[5];
  const float* Wv_r   = (const float*)d_in[6];
  const float* Wv_i   = (const float*)d_in[7];
  const float* Wo_r   = (const float*)d_in[8];
  const float* Wo_i   = (const float*)d_in[9];
  const float* bo_r   = (const float*)d_in[10];
  const float* bo_i   = (const float*)d_in[11];
  const float* ln1_gr = (const float*)d_in[12];
  const float* ln1_gi = (const float*)d_in[13];
  const float* ln1_br = (const float*)d_in[14];
  const float* ln1_bi = (const float*)d_in[15];
  const float* ln2_gr = (const float*)d_in[16];
  const float* ln2_gi = (const float*)d_in[17];
  const float* ln2_br = (const float*)d_in[18];
  const float* ln2_bi = (const float*)d_in[19];
  const float* W1_r   = (const float*)d_in[20];
  const float* W1_i   = (const float*)d_in[21];
  const float* b1_r   = (const float*)d_in[22];
  const float* b1_i   = (const float*)d_in[23];
  const float* W2_r   = (const float*)d_in[24];
  const float* W2_i   = (const float*)d_in[25];
  const float* b2_r   = (const float*)d_in[26];
  const float* b2_i   = (const float*)d_in[27];
  const float* mod_b  = (const float*)d_in[28];

  char* wsb = (char*)d_ws;
  const size_t MB = 1024*1024;
  // --- weights, bf16: 0..48 MB ---
  // QKV weights stacked [3072][1024] for the merged projection GEMM
  unsigned short* bQKV_r = (unsigned short*)(wsb + 0*MB);   // Wq_r @0, Wk_r @2MB, Wv_r @4MB
  unsigned short* bQKV_i = (unsigned short*)(wsb + 6*MB);   // Wq_i @6, Wk_i @8, Wv_i @10
  unsigned short* bWo_r = (unsigned short*)(wsb + 12*MB);
  unsigned short* bWo_i = (unsigned short*)(wsb + 14*MB);
  unsigned short* bW1_r = (unsigned short*)(wsb + 16*MB);
  unsigned short* bW1_i = (unsigned short*)(wsb + 24*MB);
  unsigned short* bW2_r = (unsigned short*)(wsb + 32*MB);
  unsigned short* bW2_i = (unsigned short*)(wsb + 40*MB);
  // --- activations: 48..96 MB ---
  unsigned short* hr  = (unsigned short*)(wsb + 48*MB);
  unsigned short* hi_ = (unsigned short*)(wsb + 52*MB);
  unsigned short* Qr  = (unsigned short*)(wsb + 56*MB);
  unsigned short* Qi  = (unsigned short*)(wsb + 60*MB);
  unsigned short* Kr  = (unsigned short*)(wsb + 64*MB);
  unsigned short* Ki  = (unsigned short*)(wsb + 68*MB);
  unsigned short* Vr  = (unsigned short*)(wsb + 72*MB);
  unsigned short* Vi  = (unsigned short*)(wsb + 76*MB);
  unsigned short* VTr = (unsigned short*)(wsb + 80*MB);
  unsigned short* VTi = (unsigned short*)(wsb + 84*MB);
  unsigned short* Or  = hr;                               // hr/hi dead after QKV gemm
  unsigned short* Oi  = hi_;
  unsigned short* h2r = Qr;                               // Q dead after attn
  unsigned short* h2i = Qi;
  unsigned short* fr  = (unsigned short*)(wsb + 64*MB);   // over K/V (dead after attn)
  unsigned short* fi  = (unsigned short*)(wsb + 80*MB);   // over VT (dead after attn)
  // --- split-K partials: 96..160 MB (guarded by ws_size) ---
  float* pR = (float*)(wsb + 96*MB);    // up to 4 x 8 MB
  float* pI = (float*)(wsb + 128*MB);   // up to 4 x 8 MB
  const bool can_split = (ws_size >= (size_t)160*MB);

  float* outR = (float*)d_out;
  float* outI = outR + (size_t)Mq*Dq;

  const dim3 blk(256);

  const int nDD = Dq*Dq;
  const int nDH = Dq*HIDq;
  cvt4_kernel<<<dim3(nDD/2048, 4), blk, 0, stream>>>(Wq_r, Wk_r, Wv_r, Wo_r,
      bQKV_r, bQKV_r + (size_t)nDD, bQKV_r + (size_t)2*nDD, bWo_r, nDD);
  cvt4_kernel<<<dim3(nDD/2048, 4), blk, 0, stream>>>(Wq_i, Wk_i, Wv_i, Wo_i,
      bQKV_i, bQKV_i + (size_t)nDD, bQKV_i + (size_t)2*nDD, bWo_i, nDD);
  cvt4_kernel<<<dim3(nDH/2048, 4), blk, 0, stream>>>(W1_r, W1_i, W2_r, W2_i,
      bW1_r, bW1_i, bW2_r, bW2_i, nDH);

  // 1. ln1
  cln_kernel<<<Mq, blk, 0, stream>>>(x_r, x_i, ln1_gr, ln1_gi, ln1_br, ln1_bi, hr, hi_);
  // 2. merged Q,K,V projection (RoPE fused on Q,K; scatter to 3 arrays)
  cgemm16_kernel<0,true,true,1><<<dim3(Mq/64, 3072/64), blk, 0, stream>>>(
      hr, hi_, bQKV_r, bQKV_i,
      Qr, Qi, Kr, Ki, Vr, Vi,
      nullptr, nullptr, nullptr, nullptr, nullptr, 3072, Dq);
  // 2b. V transpose for PV fragments
  vtrans_kernel<<<dim3(16, 32), blk, 0, stream>>>(Vr, Vi, VTr, VTi);
  // 3. flash attention (writes O over hr/hi)
  fattn_kernel<<<dim3(16, 32), blk, 0, stream>>>(Qr, Qi, Kr, Ki, VTr, VTi, Or, Oi);
  // 4. Wo + bias + residual(x) -> d_out (f32); split-K x2 when workspace allows
  if (can_split){
    cgemm16_kernel<4,false,false,2><<<dim3(Mq/64, Dq/64, 2), blk, 0, stream>>>(
        Or, Oi, bWo_r, bWo_i, pR, pI, nullptr, nullptr, nullptr, nullptr,
        nullptr, nullptr, nullptr, nullptr, nullptr, Dq, Dq);
    redk_kernel<2><<<dim3((Mq*Dq)/1024), blk, 0, stream>>>(
        pR, pI, bo_r, bo_i, x_r, x_i, outR, outI);
  } else {
    cgemm16_kernel<1,false,false,1><<<dim3(Mq/64, Dq/64), blk, 0, stream>>>(
        Or, Oi, bWo_r, bWo_i, outR, outI, nullptr, nullptr, nullptr, nullptr,
        bo_r, bo_i, x_r, x_i, nullptr, Dq, Dq);
  }
  // 5. ln2
  cln_kernel<<<Mq, blk, 0, stream>>>(outR, outI, ln2_gr, ln2_gi, ln2_br, ln2_bi, h2r, h2i);
  // 6. W1 + bias + ModReLU -> f
  cgemm16_kernel<2,false,false,1><<<dim3(Mq/64, HIDq/64), blk, 0, stream>>>(
      h2r, h2i, bW1_r, bW1_i, fr, fi, nullptr, nullptr, nullptr, nullptr,
      b1_r, b1_i, nullptr, nullptr, mod_b, HIDq, Dq);
  // 7. W2 + bias + residual(d_out) -> d_out in-place (f32); split-K x4 when possible
  if (can_split){
    cgemm16_kernel<4,false,false,4><<<dim3(Mq/64, Dq/64, 4), blk, 0, stream>>>(
        fr, fi, bW2_r, bW2_i, pR, pI, nullptr, nullptr, nullptr, nullptr,
        nullptr, nullptr, nullptr, nullptr, nullptr, Dq, HIDq);
    redk_kernel<4><<<dim3((Mq*Dq)/1024), blk, 0, stream>>>(
        pR, pI, b2_r, b2_i, outR, outI, outR, outI);
  } else {
    cgemm16_kernel<3,false,false,1><<<dim3(Mq/64, Dq/64), blk, 0, stream>>>(
        fr, fi, bW2_r, bW2_i, outR, outI, nullptr, nullptr, nullptr, nullptr,
        b2_r, b2_i, outR, outI, nullptr, Dq, HIDq);
  }
}

// Round 7
// 523.122 us; speedup vs baseline: 1.0375x; 1.0375x over previous
//
#include <hip/hip_runtime.h>

#define Bq 2
#define Lq 1024
#define Dq 1024
#define Hq 16
#define HDq 64
#define HIDq 4096
#define Mq (Bq*Lq)   // 2048

typedef __bf16 bf16x8 __attribute__((ext_vector_type(8)));
typedef float floatx4 __attribute__((ext_vector_type(4)));
typedef float floatx16 __attribute__((ext_vector_type(16)));

__device__ __forceinline__ unsigned short f2us(float f){
  unsigned u = __builtin_bit_cast(unsigned, f);
  u = u + 0x7fffu + ((u >> 16) & 1u);      // RNE to bf16
  return (unsigned short)(u >> 16);
}

// async global->LDS, 16B per lane (dest must be linear: wave base + lane*16)
__device__ __forceinline__ void gld16(const unsigned short* g, unsigned short* l){
  __builtin_amdgcn_global_load_lds(
      (const __attribute__((address_space(1))) unsigned int*)g,
      (__attribute__((address_space(3))) unsigned int*)l, 16, 0, 0);
}

// ---------------- f32 -> bf16 conversion (weights), 4 arrays per launch ----------------
__global__ __launch_bounds__(256) void cvt4_kernel(
    const float* __restrict__ s0, const float* __restrict__ s1,
    const float* __restrict__ s2, const float* __restrict__ s3,
    unsigned short* __restrict__ d0, unsigned short* __restrict__ d1,
    unsigned short* __restrict__ d2, unsigned short* __restrict__ d3,
    int n)
{
  const int a = blockIdx.y;
  const float* s = (a==0) ? s0 : (a==1) ? s1 : (a==2) ? s2 : s3;
  unsigned short* d = (a==0) ? d0 : (a==1) ? d1 : (a==2) ? d2 : d3;
  const int i = (blockIdx.x * 256 + threadIdx.x) * 8;
  if (i >= n) return;
  float4 v0 = ((const float4*)(s + i))[0];
  float4 v1 = ((const float4*)(s + i))[1];
  ushort4 o0, o1;
  o0.x=f2us(v0.x); o0.y=f2us(v0.y); o0.z=f2us(v0.z); o0.w=f2us(v0.w);
  o1.x=f2us(v1.x); o1.y=f2us(v1.y); o1.z=f2us(v1.z); o1.w=f2us(v1.w);
  ((ushort4*)(d + i))[0] = o0;
  ((ushort4*)(d + i))[1] = o1;
}

// ---------------- complex LayerNorm: f32 in, bf16 out; one block per row ----------------
__global__ __launch_bounds__(256) void cln_kernel(
    const float* __restrict__ xr, const float* __restrict__ xi,
    const float* __restrict__ gr, const float* __restrict__ gi,
    const float* __restrict__ br, const float* __restrict__ bi,
    unsigned short* __restrict__ outr, unsigned short* __restrict__ outi)
{
  const int row = blockIdx.x;
  const int t = threadIdx.x;
  const int lane = t & 63, wv = t >> 6;
  __shared__ float sred[8];

  float4 v4r = ((const float4*)(xr + (size_t)row*Dq))[t];
  float4 v4i = ((const float4*)(xi + (size_t)row*Dq))[t];
  float vr[4] = {v4r.x, v4r.y, v4r.z, v4r.w};
  float vi[4] = {v4i.x, v4i.y, v4i.z, v4i.w};
  float sr = vr[0]+vr[1]+vr[2]+vr[3];
  float si = vi[0]+vi[1]+vi[2]+vi[3];
  #pragma unroll
  for (int o=32;o>0;o>>=1){ sr += __shfl_down(sr,o,64); si += __shfl_down(si,o,64); }
  if (lane==0){ sred[wv]=sr; sred[4+wv]=si; }
  __syncthreads();
  float mr = (sred[0]+sred[1]+sred[2]+sred[3]) * (1.0f/Dq);
  float mi = (sred[4]+sred[5]+sred[6]+sred[7]) * (1.0f/Dq);
  float cr[4], ci[4], vs = 0.f;
  #pragma unroll
  for (int j=0;j<4;++j){ cr[j]=vr[j]-mr; ci[j]=vi[j]-mi; vs += cr[j]*cr[j]+ci[j]*ci[j]; }
  #pragma unroll
  for (int o=32;o>0;o>>=1) vs += __shfl_down(vs,o,64);
  __syncthreads();
  if (lane==0) sred[wv]=vs;
  __syncthreads();
  float var = (sred[0]+sred[1]+sred[2]+sred[3]) * (1.0f/Dq);
  float inv = rsqrtf(var + 1e-6f);

  float4 g4r = ((const float4*)gr)[t];
  float4 g4i = ((const float4*)gi)[t];
  float4 b4r = ((const float4*)br)[t];
  float4 b4i = ((const float4*)bi)[t];
  float grf[4] = {g4r.x,g4r.y,g4r.z,g4r.w};
  float gif[4] = {g4i.x,g4i.y,g4i.z,g4i.w};
  float brf[4] = {b4r.x,b4r.y,b4r.z,b4r.w};
  float bif[4] = {b4i.x,b4i.y,b4i.z,b4i.w};
  ushort4 o_r, o_i;
  unsigned short orr[4], oii[4];
  #pragma unroll
  for (int j=0;j<4;++j){
    float nr = cr[j]*inv, ni = ci[j]*inv;
    orr[j] = f2us(nr*grf[j] - ni*gif[j] + brf[j]);
    oii[j] = f2us(nr*gif[j] + ni*grf[j] + bif[j]);
  }
  o_r.x=orr[0]; o_r.y=orr[1]; o_r.z=orr[2]; o_r.w=orr[3];
  o_i.x=oii[0]; o_i.y=oii[1]; o_i.z=oii[2]; o_i.w=oii[3];
  ((ushort4*)(outr + (size_t)row*Dq))[t] = o_r;
  ((ushort4*)(outi + (size_t)row*Dq))[t] = o_i;
}

// ---------------- complex GEMM v6: MFMA 32x32x16, tile 64x128, dbuf, line-XOR swizzle, split-K ----
// Block: 256 threads (4 waves, 2m x 2n). Wave tile 32(M) x 64(N): reads/FLOP = 1/42.7 B
// (1.33x less LDS-read than 32x32 wave tile). acc = 4 products x 2 nf x 16 = 128 regs.
// LDS: rows stored as 128B row-pair lines; chunk c at line L holds logical chunk (c^(L&7)),
// staged via gld16 (linear dest) with the inverse swizzle on the per-lane GLOBAL source.
// A planes 64x32 (4KB), W planes 128x32 (8KB); dbuf total 48KB -> 3 blocks/CU.
// EPI: 0 plain bf16; 1 +bias+resid(f32)->f32; 2 +bias+ModReLU->bf16; 3 = 1;
//      4 raw f32 partial (split-K: blockIdx.z selects K-chunk and partial buffer).
// SPLIT3: output scattered to 3 arrays of stride 1024 by n0>>10 (merged QKV).
template<int EPI, bool ROPE, bool SPLIT3, int SPLITK>
__global__ __launch_bounds__(256,2) void cgemm_kernel(
    const unsigned short* __restrict__ Ar, const unsigned short* __restrict__ Ai,
    const unsigned short* __restrict__ Wr, const unsigned short* __restrict__ Wi,
    void* __restrict__ Cr0, void* __restrict__ Ci0,
    void* __restrict__ Cr1, void* __restrict__ Ci1,
    void* __restrict__ Cr2, void* __restrict__ Ci2,
    const float* __restrict__ biasR, const float* __restrict__ biasI,
    const float* __restrict__ resR, const float* __restrict__ resI,
    const float* __restrict__ modb,
    int Ndim, int Kdim)
{
  const int t = threadIdx.x;
  const int w = t >> 6, l = t & 63;
  const int l31 = l & 31, lhi = l >> 5;
  const int wm = w >> 1, wn = w & 1;
  const int m0 = blockIdx.x * 64, n0 = blockIdx.y * 128;
  const int kbase = (SPLITK > 1) ? (int)blockIdx.z * (Kdim / SPLITK) : 0;
  const int Klen = Kdim / SPLITK;

  __shared__ __align__(16) unsigned short sAr0[2048], sAi0[2048], sWr0[4096], sWi0[4096];
  __shared__ __align__(16) unsigned short sAr1[2048], sAi1[2048], sWr1[4096], sWi1[4096];

  floatx16 accRR[2], accII[2], accRI[2], accIR[2];
  #pragma unroll
  for (int i=0;i<2;++i){
    #pragma unroll
    for (int r=0;r<16;++r){ accRR[i][r]=0.f; accII[i][r]=0.f; accRI[i][r]=0.f; accIR[i][r]=0.f; }
  }

  // ---- staging decode: physical 16B slot -> (row, kchunk) via inverse swizzle ----
  // slot s: line = s>>3, cphys = s&7, clog = cphys ^ (line&7), row = line*2 + (clog>>2),
  // kchunk = clog&3. Global src = row*Kdim + kchunk*8 (+ kbase + k-step offset).
  const int lnA = t >> 3, cpA = t & 7;
  const int clA = cpA ^ (lnA & 7);
  const int rwA = lnA*2 + (clA >> 2), kcA = clA & 3;
  const unsigned short* pAr = Ar + (size_t)(m0 + rwA)*Kdim + kcA*8 + kbase;
  const unsigned short* pAi = Ai + (size_t)(m0 + rwA)*Kdim + kcA*8 + kbase;
  const int dA = t*8;
  // W slots t and t+256
  const int ln1 = (t+256) >> 3, cp1 = t & 7;
  const int cl1 = cp1 ^ (ln1 & 7);
  const int rw1 = ln1*2 + (cl1 >> 2), kc1 = cl1 & 3;
  const unsigned short* pWr0 = Wr + (size_t)(n0 + rwA)*Kdim + kcA*8 + kbase;
  const unsigned short* pWi0 = Wi + (size_t)(n0 + rwA)*Kdim + kcA*8 + kbase;
  const unsigned short* pWr1 = Wr + (size_t)(n0 + rw1)*Kdim + kc1*8 + kbase;
  const unsigned short* pWi1 = Wi + (size_t)(n0 + rw1)*Kdim + kc1*8 + kbase;
  const int dW1 = (t+256)*8;

  // ---- fragment read offsets (swizzled), per k16-slice s: kchunk = s*2 + lhi ----
  const int rA = wm*32 + l31;
  const int lnRA = rA >> 1, bA = (rA & 1)*4;
  int aoff[2];
  #pragma unroll
  for (int s=0;s<2;++s) aoff[s] = lnRA*64 + (((bA + s*2 + lhi) ^ (lnRA & 7)) * 8);
  const int rW0 = wn*64 + l31,      lnW0 = rW0 >> 1, bW0 = (rW0 & 1)*4;
  const int rW1 = wn*64 + 32 + l31, lnW1 = rW1 >> 1, bW1 = (rW1 & 1)*4;
  int woff0[2], woff1[2];
  #pragma unroll
  for (int s=0;s<2;++s){
    woff0[s] = lnW0*64 + (((bW0 + s*2 + lhi) ^ (lnW0 & 7)) * 8);
    woff1[s] = lnW1*64 + (((bW1 + s*2 + lhi) ^ (lnW1 & 7)) * 8);
  }

#define STAGEK(SA, SB, SC, SD, KOFF) do{                                   \
    gld16(pAr  + (KOFF), &SA[dA]);                                         \
    gld16(pAi  + (KOFF), &SB[dA]);                                         \
    gld16(pWr0 + (KOFF), &SC[dA]);                                         \
    gld16(pWi0 + (KOFF), &SD[dA]);                                         \
    gld16(pWr1 + (KOFF), &SC[dW1]);                                        \
    gld16(pWi1 + (KOFF), &SD[dW1]);                                        \
  }while(0)

#define COMPUTEK(SA, SB, SC, SD) do{                                       \
    _Pragma("unroll")                                                      \
    for (int s_=0; s_<2; ++s_){                                            \
      bf16x8 fAr  = *(const bf16x8*)&SA[aoff[s_]];                         \
      bf16x8 fAi  = *(const bf16x8*)&SB[aoff[s_]];                         \
      bf16x8 fW0r = *(const bf16x8*)&SC[woff0[s_]];                        \
      bf16x8 fW0i = *(const bf16x8*)&SD[woff0[s_]];                        \
      bf16x8 fW1r = *(const bf16x8*)&SC[woff1[s_]];                        \
      bf16x8 fW1i = *(const bf16x8*)&SD[woff1[s_]];                        \
      accRR[0] = __builtin_amdgcn_mfma_f32_32x32x16_bf16(fAr, fW0r, accRR[0], 0,0,0); \
      accII[0] = __builtin_amdgcn_mfma_f32_32x32x16_bf16(fAi, fW0i, accII[0], 0,0,0); \
      accRI[0] = __builtin_amdgcn_mfma_f32_32x32x16_bf16(fAr, fW0i, accRI[0], 0,0,0); \
      accIR[0] = __builtin_amdgcn_mfma_f32_32x32x16_bf16(fAi, fW0r, accIR[0], 0,0,0); \
      accRR[1] = __builtin_amdgcn_mfma_f32_32x32x16_bf16(fAr, fW1r, accRR[1], 0,0,0); \
      accII[1] = __builtin_amdgcn_mfma_f32_32x32x16_bf16(fAi, fW1i, accII[1], 0,0,0); \
      accRI[1] = __builtin_amdgcn_mfma_f32_32x32x16_bf16(fAr, fW1i, accRI[1], 0,0,0); \
      accIR[1] = __builtin_amdgcn_mfma_f32_32x32x16_bf16(fAi, fW1r, accIR[1], 0,0,0); \
    } }while(0)

  const int nk = Klen >> 5;          // 16/32 -- always even
  STAGEK(sAr0, sAi0, sWr0, sWi0, 0);
  __syncthreads();
  for (int kk=0; kk<nk; kk+=2){
    STAGEK(sAr1, sAi1, sWr1, sWi1, (size_t)(kk+1)*32);
    COMPUTEK(sAr0, sAi0, sWr0, sWi0);
    __syncthreads();                              // drains stage(buf1); frees buf0
    if (kk+2 < nk) STAGEK(sAr0, sAi0, sWr0, sWi0, (size_t)(kk+2)*32);
    COMPUTEK(sAr1, sAi1, sWr1, sWi1);
    __syncthreads();                              // drains stage(buf0); frees buf1
  }
#undef STAGEK
#undef COMPUTEK

  // ---- epilogue: C 32x32 layout: col = l31, row = (r&3) + 8*(r>>2) + 4*lhi ----
  float cr[2][16], ci[2][16];
  #pragma unroll
  for (int nf=0; nf<2; ++nf)
    #pragma unroll
    for (int r=0;r<16;++r){
      cr[nf][r] = accRR[nf][r] - accII[nf][r];
      ci[nf][r] = accRI[nf][r] + accIR[nf][r];
    }

  // RoPE: this wave's 64 cols = exactly one head; d = nf*32 + l31, pair (d,d+32) = (nf0,nf1)
  const bool doRope = ROPE && (!SPLIT3 || (n0 < 2048));
  if (doRope){
    const float invf = powf(10000.0f, -(float)l31 * (1.0f/32.0f));
    #pragma unroll
    for (int r=0;r<16;++r){
      const int gm = m0 + wm*32 + (r&3) + 8*(r>>2) + 4*lhi;
      float s, c;
      sincosf((float)(gm & (Lq-1)) * invf, &s, &c);
      float xr_ = cr[0][r], yr_ = cr[1][r];
      cr[0][r] = xr_*c - yr_*s;  cr[1][r] = yr_*c + xr_*s;
      float xi_ = ci[0][r], yi_ = ci[1][r];
      ci[0][r] = xi_*c - yi_*s;  ci[1][r] = yi_*c + xi_*s;
    }
  }

  unsigned short *oR16 = nullptr, *oI16 = nullptr;
  float *oR32 = nullptr, *oI32 = nullptr;
  int ncol0, Nst;
  if (SPLIT3){
    const int aid = n0 >> 10;
    void* vr = (aid==0) ? Cr0 : ((aid==1) ? Cr1 : Cr2);
    void* vi = (aid==0) ? Ci0 : ((aid==1) ? Ci1 : Ci2);
    oR16 = (unsigned short*)vr; oI16 = (unsigned short*)vi;
    ncol0 = n0 & 1023; Nst = 1024;
  } else {
    oR16 = (unsigned short*)Cr0; oI16 = (unsigned short*)Ci0;
    oR32 = (float*)Cr0;          oI32 = (float*)Ci0;
    ncol0 = n0; Nst = Ndim;
  }
  if (EPI == 4){
    const size_t pstride = (size_t)Mq * Ndim;
    oR32 = (float*)Cr0 + (size_t)blockIdx.z * pstride;
    oI32 = (float*)Ci0 + (size_t)blockIdx.z * pstride;
  }

  #pragma unroll
  for (int nf=0; nf<2; ++nf){
    const int gn = n0 + wn*64 + nf*32 + l31;      // full-N index (bias/modb)
    const int cn = ncol0 + wn*64 + nf*32 + l31;   // output-array col
    float bR = 0.f, bI = 0.f, mb = 0.f;
    if (EPI >= 1 && EPI <= 3){ bR = biasR[gn]; bI = biasI[gn]; }
    if (EPI == 2){ mb = modb[gn]; }
    #pragma unroll
    for (int r=0;r<16;++r){
      const int gm = m0 + wm*32 + (r&3) + 8*(r>>2) + 4*lhi;
      const size_t idx = (size_t)gm*Nst + cn;
      float vr_ = cr[nf][r] + bR, vi_ = ci[nf][r] + bI;
      if (EPI == 1 || EPI == 3){ vr_ += resR[idx]; vi_ += resI[idx]; }
      if (EPI == 2){
        float mag = sqrtf(vr_*vr_ + vi_*vi_);
        float safe = (mag > 0.f) ? mag : 1.0f;
        float act = fmaxf(mag + mb, 0.f);
        float sc = act / safe;
        vr_ *= sc; vi_ *= sc;
      }
      if (EPI == 0 || EPI == 2){
        oR16[idx] = f2us(vr_);
        oI16[idx] = f2us(vi_);
      } else {
        oR32[idx] = vr_;
        oI32[idx] = vi_;
      }
    }
  }
}

// ---------------- split-K reduce: out = sum(partials) + bias + resid (f32) ----------------
template<int NS>
__global__ __launch_bounds__(256) void redk_kernel(
    const float* __restrict__ pR, const float* __restrict__ pI,
    const float* __restrict__ bR, const float* __restrict__ bI,
    const float* __restrict__ rR, const float* __restrict__ rI,
    float* __restrict__ oR, float* __restrict__ oI)
{
  const size_t MN = (size_t)Mq * Dq;
  const size_t i = ((size_t)blockIdx.x * 256 + threadIdx.x) * 4;
  const int col = (int)(i & (Dq - 1));
  float4 br = *(const float4*)(bR + col);
  float4 bi = *(const float4*)(bI + col);
  float4 xr = *(const float4*)(rR + i);
  float4 xi = *(const float4*)(rI + i);
  float ar0 = br.x + xr.x, ar1 = br.y + xr.y, ar2 = br.z + xr.z, ar3 = br.w + xr.w;
  float ai0 = bi.x + xi.x, ai1 = bi.y + xi.y, ai2 = bi.z + xi.z, ai3 = bi.w + xi.w;
  #pragma unroll
  for (int s=0; s<NS; ++s){
    float4 qr = *(const float4*)(pR + s*MN + i);
    float4 qi = *(const float4*)(pI + s*MN + i);
    ar0 += qr.x; ar1 += qr.y; ar2 += qr.z; ar3 += qr.w;
    ai0 += qi.x; ai1 += qi.y; ai2 += qi.z; ai3 += qi.w;
  }
  float4 orv = {ar0, ar1, ar2, ar3};
  float4 oiv = {ai0, ai1, ai2, ai3};
  *(float4*)(oR + i) = orv;
  *(float4*)(oI + i) = oiv;
}

// ---------------- V transpose: V[b,l,h*64+d] -> VT[(b*16+h)*64+d][l] ----------------
__global__ __launch_bounds__(256) void vtrans_kernel(
    const unsigned short* __restrict__ Vr, const unsigned short* __restrict__ Vi,
    unsigned short* __restrict__ VTr, unsigned short* __restrict__ VTi)
{
  const int lt = blockIdx.x;      // 0..15 (L tile)
  const int bh = blockIdx.y;      // 0..31
  const int h = bh & (Hq-1), b = bh >> 4;
  const int t = threadIdx.x;
  __shared__ unsigned short sTr[64*65], sTi[64*65];

  const int row = t >> 2;          // l-local 0..63
  const int dc  = (t & 3) * 16;    // d chunk
  const size_t g = ((size_t)(b*Lq) + lt*64 + row)*Dq + h*HDq + dc;
  uint4 a0 = *(const uint4*)(Vr + g);
  uint4 a1 = *(const uint4*)(Vr + g + 8);
  uint4 b0 = *(const uint4*)(Vi + g);
  uint4 b1 = *(const uint4*)(Vi + g + 8);
  const unsigned short* pa0 = (const unsigned short*)&a0;
  const unsigned short* pa1 = (const unsigned short*)&a1;
  const unsigned short* pb0 = (const unsigned short*)&b0;
  const unsigned short* pb1 = (const unsigned short*)&b1;
  #pragma unroll
  for (int e=0;e<8;++e){
    sTr[(dc+e)*65 + row]   = pa0[e];
    sTr[(dc+8+e)*65 + row] = pa1[e];
    sTi[(dc+e)*65 + row]   = pb0[e];
    sTi[(dc+8+e)*65 + row] = pb1[e];
  }
  __syncthreads();
  const int d  = t >> 2;
  const int lcx = (t & 3) * 16;
  unsigned short bufr[16], bufi[16];
  #pragma unroll
  for (int e=0;e<16;++e){
    bufr[e] = sTr[d*65 + lcx + e];
    bufi[e] = sTi[d*65 + lcx + e];
  }
  const size_t og = ((size_t)bh*HDq + d)*Lq + lt*64 + lcx;
  *(uint4*)(VTr + og)     = *(const uint4*)&bufr[0];
  *(uint4*)(VTr + og + 8) = *(const uint4*)&bufr[8];
  *(uint4*)(VTi + og)     = *(const uint4*)&bufi[0];
  *(uint4*)(VTi + og + 8) = *(const uint4*)&bufi[8];
}

// ---------------- flash attention: 64x64 tiles, MFMA, online softmax ----------------
__device__ __forceinline__ int swz(int v){ return v ^ ((v >> 4) & 7); }

__global__ __launch_bounds__(256,2) void fattn_kernel(
    const unsigned short* __restrict__ Qr, const unsigned short* __restrict__ Qi,
    const unsigned short* __restrict__ Kr, const unsigned short* __restrict__ Ki,
    const unsigned short* __restrict__ VTr, const unsigned short* __restrict__ VTi,
    unsigned short* __restrict__ Or, unsigned short* __restrict__ Oi)
{
  const int qt = (int)(gridDim.x - 1 - blockIdx.x);   // big tiles dispatch first
  const int bh = blockIdx.y;
  const int h = bh & (Hq-1), b = bh >> 4;
  const int t = threadIdx.x;
  const int w = t >> 6, lane = t & 63;
  const int quad = lane >> 4, l15 = lane & 15;

  __shared__ __align__(16) unsigned short sKr[4096], sKi[4096], sVr[4096], sVi[4096];
  __shared__ __align__(16) unsigned short sP[64*72];

  const size_t qbase = ((size_t)(b*Lq) + qt*64 + w*16 + l15)*Dq + h*HDq;
  bf16x8 qr_lo = *(const bf16x8*)(Qr + qbase + quad*8);
  bf16x8 qr_hi = *(const bf16x8*)(Qr + qbase + 32 + quad*8);
  bf16x8 qi_lo = *(const bf16x8*)(Qi + qbase + quad*8);
  bf16x8 qi_hi = *(const bf16x8*)(Qi + qbase + 32 + quad*8);

  const floatx4 fzero = {0.f,0.f,0.f,0.f};
  floatx4 aOr[4], aOi[4];
  #pragma unroll
  for (int i=0;i<4;++i){ aOr[i]=fzero; aOi[i]=fzero; }
  float m_run[4] = {-1e30f,-1e30f,-1e30f,-1e30f};
  float l_run[4] = {0.f,0.f,0.f,0.f};

  const int srow = t >> 2;
  const int sns  = srow >> 4;
  const int sl15 = srow & 15;
  const int q8   = (t & 3) * 2;
  const int dstA = sns*1024 + swz(q8*16 + sl15)*8;
  const int dstB = sns*1024 + swz((q8+1)*16 + sl15)*8;

  const int rd0 = swz(quad*16 + l15)*8;
  const int rd1 = swz((4+quad)*16 + l15)*8;

  for (int kt = 0; kt <= qt; ++kt){
    const size_t kg = ((size_t)(b*Lq) + kt*64 + srow)*Dq + h*HDq + q8*8;
    uint4 ka = *(const uint4*)(Kr + kg);
    uint4 kb = *(const uint4*)(Kr + kg + 8);
    uint4 kc = *(const uint4*)(Ki + kg);
    uint4 kd = *(const uint4*)(Ki + kg + 8);
    const size_t vg = ((size_t)bh*HDq + srow)*Lq + kt*64 + q8*8;
    uint4 va = *(const uint4*)(VTr + vg);
    uint4 vb = *(const uint4*)(VTr + vg + 8);
    uint4 vc = *(const uint4*)(VTi + vg);
    uint4 vd = *(const uint4*)(VTi + vg + 8);
    __syncthreads();
    *(uint4*)&sKr[dstA] = ka;  *(uint4*)&sKr[dstB] = kb;
    *(uint4*)&sKi[dstA] = kc;  *(uint4*)&sKi[dstB] = kd;
    *(uint4*)&sVr[dstA] = va;  *(uint4*)&sVr[dstB] = vb;
    *(uint4*)&sVi[dstA] = vc;  *(uint4*)&sVi[dstB] = vd;
    __syncthreads();

    floatx4 sc[4];
    #pragma unroll
    for (int ns=0; ns<4; ++ns){
      floatx4 x = fzero;
      x = __builtin_amdgcn_mfma_f32_16x16x32_bf16(qr_lo, *(const bf16x8*)&sKr[ns*1024 + rd0], x, 0,0,0);
      x = __builtin_amdgcn_mfma_f32_16x16x32_bf16(qr_hi, *(const bf16x8*)&sKr[ns*1024 + rd1], x, 0,0,0);
      x = __builtin_amdgcn_mfma_f32_16x16x32_bf16(qi_lo, *(const bf16x8*)&sKi[ns*1024 + rd0], x, 0,0,0);
      x = __builtin_amdgcn_mfma_f32_16x16x32_bf16(qi_hi, *(const bf16x8*)&sKi[ns*1024 + rd1], x, 0,0,0);
      sc[ns] = x;
    }

    const bool diag = (kt == qt);
    float rmax[4] = {-1e30f,-1e30f,-1e30f,-1e30f};
    #pragma unroll
    for (int ns=0; ns<4; ++ns){
      #pragma unroll
      for (int r=0; r<4; ++r){
        float s = sc[ns][r] * 0.125f;
        if (diag && (ns*16 + l15 > w*16 + quad*4 + r)) s = -1e30f;
        sc[ns][r] = s;
        rmax[r] = fmaxf(rmax[r], s);
      }
    }
    #pragma unroll
    for (int off=1; off<16; off<<=1){
      #pragma unroll
      for (int r=0; r<4; ++r) rmax[r] = fmaxf(rmax[r], __shfl_xor(rmax[r], off, 64));
    }

    float alpha[4], rsum[4];
    #pragma unroll
    for (int r=0; r<4; ++r){
      float mn = fmaxf(m_run[r], rmax[r]);
      alpha[r] = __expf(m_run[r] - mn);
      m_run[r] = mn;
      rsum[r] = 0.f;
    }
    #pragma unroll
    for (int ns=0; ns<4; ++ns){
      #pragma unroll
      for (int r=0; r<4; ++r){
        float p = __expf(sc[ns][r] - m_run[r]);
        rsum[r] += p;
        sP[(w*16 + quad*4 + r)*72 + ns*16 + l15] = f2us(p);
      }
    }
    #pragma unroll
    for (int off=1; off<16; off<<=1){
      #pragma unroll
      for (int r=0; r<4; ++r) rsum[r] += __shfl_xor(rsum[r], off, 64);
    }
    #pragma unroll
    for (int r=0; r<4; ++r) l_run[r] = l_run[r]*alpha[r] + rsum[r];
    #pragma unroll
    for (int ds=0; ds<4; ++ds)
      #pragma unroll
      for (int r=0; r<4; ++r){ aOr[ds][r] *= alpha[r]; aOi[ds][r] *= alpha[r]; }

    #pragma unroll
    for (int step=0; step<2; ++step){
      bf16x8 pf = *(const bf16x8*)&sP[(w*16 + l15)*72 + step*32 + quad*8];
      const int ro = (step==0) ? rd0 : rd1;
      #pragma unroll
      for (int ds=0; ds<4; ++ds){
        aOr[ds] = __builtin_amdgcn_mfma_f32_16x16x32_bf16(pf, *(const bf16x8*)&sVr[ds*1024 + ro], aOr[ds], 0,0,0);
        aOi[ds] = __builtin_amdgcn_mfma_f32_16x16x32_bf16(pf, *(const bf16x8*)&sVi[ds*1024 + ro], aOi[ds], 0,0,0);
      }
    }
  }

  #pragma unroll
  for (int r=0; r<4; ++r){
    const float il = 1.0f / l_run[r];
    const size_t ob = ((size_t)(b*Lq) + qt*64 + w*16 + quad*4 + r)*Dq + h*HDq;
    #pragma unroll
    for (int ds=0; ds<4; ++ds){
      Or[ob + ds*16 + l15] = f2us(aOr[ds][r] * il);
      Oi[ob + ds*16 + l15] = f2us(aOi[ds][r] * il);
    }
  }
}

// ---------------- launch ----------------
extern "C" void kernel_launch(void* const* d_in, const int* in_sizes, int n_in,
                              void* d_out, int out_size, void* d_ws, size_t ws_size,
                              hipStream_t stream)
{
  const float* x_r    = (const float*)d_in[0];
  const float* x_i    = (const float*)d_in[1];
  const float* Wq_r   = (const float*)d_in[2];
  const float* Wq_i   = (const float*)d_in[3];
  const float* Wk_r   = (const float*)d_in[4];
  const float* Wk_i   = (const float*)d_in[5];
  const float* Wv_r   = (const float*)d_in[6];
  const float* Wv_i   = (const float*)d_in[7];
  const float* Wo_r   = (const float*)d_in[8];
  const float* Wo_i   = (const float*)d_in[9];
  const float* bo_r   = (const float*)d_in[10];
  const float* bo_i   = (const float*)d_in[11];
  const float* ln1_gr = (const float*)d_in[12];
  const float* ln1_gi = (const float*)d_in[13];
  const float* ln1_br = (const float*)d_in[14];
  const float* ln1_bi = (const float*)d_in[15];
  const float* ln2_gr = (const float*)d_in[16];
  const float* ln2_gi = (const float*)d_in[17];
  const float* ln2_br = (const float*)d_in[18];
  const float* ln2_bi = (const float*)d_in[19];
  const float* W1_r   = (const float*)d_in[20];
  const float* W1_i   = (const float*)d_in[21];
  const float* b1_r   = (const float*)d_in[22];
  const float* b1_i   = (const float*)d_in[23];
  const float* W2_r   = (const float*)d_in[24];
  const float* W2_i   = (const float*)d_in[25];
  const float* b2_r   = (const float*)d_in[26];
  const float* b2_i   = (const float*)d_in[27];
  const float* mod_b  = (const float*)d_in[28];

  char* wsb = (char*)d_ws;
  const size_t MB = 1024*1024;
  // --- weights, bf16: 0..48 MB ---
  // QKV weights stacked [3072][1024] for the merged projection GEMM
  unsigned short* bQKV_r = (unsigned short*)(wsb + 0*MB);   // Wq_r @0, Wk_r @2MB, Wv_r @4MB
  unsigned short* bQKV_i = (unsigned short*)(wsb + 6*MB);   // Wq_i @6, Wk_i @8, Wv_i @10
  unsigned short* bWo_r = (unsigned short*)(wsb + 12*MB);
  unsigned short* bWo_i = (unsigned short*)(wsb + 14*MB);
  unsigned short* bW1_r = (unsigned short*)(wsb + 16*MB);
  unsigned short* bW1_i = (unsigned short*)(wsb + 24*MB);
  unsigned short* bW2_r = (unsigned short*)(wsb + 32*MB);
  unsigned short* bW2_i = (unsigned short*)(wsb + 40*MB);
  // --- activations: 48..96 MB ---
  unsigned short* hr  = (unsigned short*)(wsb + 48*MB);
  unsigned short* hi_ = (unsigned short*)(wsb + 52*MB);
  unsigned short* Qr  = (unsigned short*)(wsb + 56*MB);
  unsigned short* Qi  = (unsigned short*)(wsb + 60*MB);
  unsigned short* Kr  = (unsigned short*)(wsb + 64*MB);
  unsigned short* Ki  = (unsigned short*)(wsb + 68*MB);
  unsigned short* Vr  = (unsigned short*)(wsb + 72*MB);
  unsigned short* Vi  = (unsigned short*)(wsb + 76*MB);
  unsigned short* VTr = (unsigned short*)(wsb + 80*MB);
  unsigned short* VTi = (unsigned short*)(wsb + 84*MB);
  unsigned short* Or  = hr;                               // hr/hi dead after QKV gemm
  unsigned short* Oi  = hi_;
  unsigned short* h2r = Qr;                               // Q dead after attn
  unsigned short* h2i = Qi;
  unsigned short* fr  = (unsigned short*)(wsb + 64*MB);   // over K/V (dead after attn)
  unsigned short* fi  = (unsigned short*)(wsb + 80*MB);   // over VT (dead after attn)
  // --- split-K partials: 96..160 MB (guarded by ws_size) ---
  float* pR = (float*)(wsb + 96*MB);    // up to 4 x 8 MB
  float* pI = (float*)(wsb + 128*MB);   // up to 4 x 8 MB
  const bool can_split = (ws_size >= (size_t)160*MB);

  float* outR = (float*)d_out;
  float* outI = outR + (size_t)Mq*Dq;

  const dim3 blk(256);

  const int nDD = Dq*Dq;
  const int nDH = Dq*HIDq;
  cvt4_kernel<<<dim3(nDD/2048, 4), blk, 0, stream>>>(Wq_r, Wk_r, Wv_r, Wo_r,
      bQKV_r, bQKV_r + (size_t)nDD, bQKV_r + (size_t)2*nDD, bWo_r, nDD);
  cvt4_kernel<<<dim3(nDD/2048, 4), blk, 0, stream>>>(Wq_i, Wk_i, Wv_i, Wo_i,
      bQKV_i, bQKV_i + (size_t)nDD, bQKV_i + (size_t)2*nDD, bWo_i, nDD);
  cvt4_kernel<<<dim3(nDH/2048, 4), blk, 0, stream>>>(W1_r, W1_i, W2_r, W2_i,
      bW1_r, bW1_i, bW2_r, bW2_i, nDH);

  // 1. ln1
  cln_kernel<<<Mq, blk, 0, stream>>>(x_r, x_i, ln1_gr, ln1_gi, ln1_br, ln1_bi, hr, hi_);
  // 2. merged Q,K,V projection (RoPE fused on Q,K; scatter to 3 arrays)
  cgemm_kernel<0,true,true,1><<<dim3(Mq/64, 3072/128), blk, 0, stream>>>(
      hr, hi_, bQKV_r, bQKV_i,
      Qr, Qi, Kr, Ki, Vr, Vi,
      nullptr, nullptr, nullptr, nullptr, nullptr, 3072, Dq);
  // 2b. V transpose for PV fragments
  vtrans_kernel<<<dim3(16, 32), blk, 0, stream>>>(Vr, Vi, VTr, VTi);
  // 3. flash attention (writes O over hr/hi)
  fattn_kernel<<<dim3(16, 32), blk, 0, stream>>>(Qr, Qi, Kr, Ki, VTr, VTi, Or, Oi);
  // 4. Wo + bias + residual(x) -> d_out (f32); split-K x2 when workspace allows
  if (can_split){
    cgemm_kernel<4,false,false,2><<<dim3(Mq/64, Dq/128, 2), blk, 0, stream>>>(
        Or, Oi, bWo_r, bWo_i, pR, pI, nullptr, nullptr, nullptr, nullptr,
        nullptr, nullptr, nullptr, nullptr, nullptr, Dq, Dq);
    redk_kernel<2><<<dim3((Mq*Dq)/1024), blk, 0, stream>>>(
        pR, pI, bo_r, bo_i, x_r, x_i, outR, outI);
  } else {
    cgemm_kernel<1,false,false,1><<<dim3(Mq/64, Dq/128), blk, 0, stream>>>(
        Or, Oi, bWo_r, bWo_i, outR, outI, nullptr, nullptr, nullptr, nullptr,
        bo_r, bo_i, x_r, x_i, nullptr, Dq, Dq);
  }
  // 5. ln2
  cln_kernel<<<Mq, blk, 0, stream>>>(outR, outI, ln2_gr, ln2_gi, ln2_br, ln2_bi, h2r, h2i);
  // 6. W1 + bias + ModReLU -> f
  cgemm_kernel<2,false,false,1><<<dim3(Mq/64, HIDq/128), blk, 0, stream>>>(
      h2r, h2i, bW1_r, bW1_i, fr, fi, nullptr, nullptr, nullptr, nullptr,
      b1_r, b1_i, nullptr, nullptr, mod_b, HIDq, Dq);
  // 7. W2 + bias + residual(d_out) -> d_out in-place (f32); split-K x4 when possible
  if (can_split){
    cgemm_kernel<4,false,false,4><<<dim3(Mq/64, Dq/128, 4), blk, 0, stream>>>(
        fr, fi, bW2_r, bW2_i, pR, pI, nullptr, nullptr, nullptr, nullptr,
        nullptr, nullptr, nullptr, nullptr, nullptr, Dq, HIDq);
    redk_kernel<4><<<dim3((Mq*Dq)/1024), blk, 0, stream>>>(
        pR, pI, b2_r, b2_i, outR, outI, outR, outI);
  } else {
    cgemm_kernel<3,false,false,1><<<dim3(Mq/64, Dq/128), blk, 0, stream>>>(
        fr, fi, bW2_r, bW2_i, outR, outI, nullptr, nullptr, nullptr, nullptr,
        b2_r, b2_i, outR, outI, nullptr, Dq, HIDq);
  }
}

// Round 8
// 488.091 us; speedup vs baseline: 1.1120x; 1.0718x over previous
//
#include <hip/hip_runtime.h>

#define Bq 2
#define Lq 1024
#define Dq 1024
#define Hq 16
#define HDq 64
#define HIDq 4096
#define Mq (Bq*Lq)   // 2048

typedef __bf16 bf16x8 __attribute__((ext_vector_type(8)));
typedef float floatx4 __attribute__((ext_vector_type(4)));

__device__ __forceinline__ unsigned short f2us(float f){
  unsigned u = __builtin_bit_cast(unsigned, f);
  u = u + 0x7fffu + ((u >> 16) & 1u);      // RNE to bf16
  return (unsigned short)(u >> 16);
}

// async global->LDS, 16B per lane (dest must be linear: wave base + lane*16)
__device__ __forceinline__ void gld16(const unsigned short* g, unsigned short* l){
  __builtin_amdgcn_global_load_lds(
      (const __attribute__((address_space(1))) unsigned int*)g,
      (__attribute__((address_space(3))) unsigned int*)l, 16, 0, 0);
}

// ---------------- f32 -> bf16 conversion (weights), 4 arrays per launch ----------------
__global__ __launch_bounds__(256) void cvt4_kernel(
    const float* __restrict__ s0, const float* __restrict__ s1,
    const float* __restrict__ s2, const float* __restrict__ s3,
    unsigned short* __restrict__ d0, unsigned short* __restrict__ d1,
    unsigned short* __restrict__ d2, unsigned short* __restrict__ d3,
    int n)
{
  const int a = blockIdx.y;
  const float* s = (a==0) ? s0 : (a==1) ? s1 : (a==2) ? s2 : s3;
  unsigned short* d = (a==0) ? d0 : (a==1) ? d1 : (a==2) ? d2 : d3;
  const int i = (blockIdx.x * 256 + threadIdx.x) * 8;
  if (i >= n) return;
  float4 v0 = ((const float4*)(s + i))[0];
  float4 v1 = ((const float4*)(s + i))[1];
  ushort4 o0, o1;
  o0.x=f2us(v0.x); o0.y=f2us(v0.y); o0.z=f2us(v0.z); o0.w=f2us(v0.w);
  o1.x=f2us(v1.x); o1.y=f2us(v1.y); o1.z=f2us(v1.z); o1.w=f2us(v1.w);
  ((ushort4*)(d + i))[0] = o0;
  ((ushort4*)(d + i))[1] = o1;
}

// ---------------- complex LayerNorm: f32 in, bf16 out; one block per row ----------------
__global__ __launch_bounds__(256) void cln_kernel(
    const float* __restrict__ xr, const float* __restrict__ xi,
    const float* __restrict__ gr, const float* __restrict__ gi,
    const float* __restrict__ br, const float* __restrict__ bi,
    unsigned short* __restrict__ outr, unsigned short* __restrict__ outi)
{
  const int row = blockIdx.x;
  const int t = threadIdx.x;
  const int lane = t & 63, wv = t >> 6;
  __shared__ float sred[8];

  float4 v4r = ((const float4*)(xr + (size_t)row*Dq))[t];
  float4 v4i = ((const float4*)(xi + (size_t)row*Dq))[t];
  float vr[4] = {v4r.x, v4r.y, v4r.z, v4r.w};
  float vi[4] = {v4i.x, v4i.y, v4i.z, v4i.w};
  float sr = vr[0]+vr[1]+vr[2]+vr[3];
  float si = vi[0]+vi[1]+vi[2]+vi[3];
  #pragma unroll
  for (int o=32;o>0;o>>=1){ sr += __shfl_down(sr,o,64); si += __shfl_down(si,o,64); }
  if (lane==0){ sred[wv]=sr; sred[4+wv]=si; }
  __syncthreads();
  float mr = (sred[0]+sred[1]+sred[2]+sred[3]) * (1.0f/Dq);
  float mi = (sred[4]+sred[5]+sred[6]+sred[7]) * (1.0f/Dq);
  float cr[4], ci[4], vs = 0.f;
  #pragma unroll
  for (int j=0;j<4;++j){ cr[j]=vr[j]-mr; ci[j]=vi[j]-mi; vs += cr[j]*cr[j]+ci[j]*ci[j]; }
  #pragma unroll
  for (int o=32;o>0;o>>=1) vs += __shfl_down(vs,o,64);
  __syncthreads();
  if (lane==0) sred[wv]=vs;
  __syncthreads();
  float var = (sred[0]+sred[1]+sred[2]+sred[3]) * (1.0f/Dq);
  float inv = rsqrtf(var + 1e-6f);

  float4 g4r = ((const float4*)gr)[t];
  float4 g4i = ((const float4*)gi)[t];
  float4 b4r = ((const float4*)br)[t];
  float4 b4i = ((const float4*)bi)[t];
  float grf[4] = {g4r.x,g4r.y,g4r.z,g4r.w};
  float gif[4] = {g4i.x,g4i.y,g4i.z,g4i.w};
  float brf[4] = {b4r.x,b4r.y,b4r.z,b4r.w};
  float bif[4] = {b4i.x,b4i.y,b4i.z,b4i.w};
  ushort4 o_r, o_i;
  unsigned short orr[4], oii[4];
  #pragma unroll
  for (int j=0;j<4;++j){
    float nr = cr[j]*inv, ni = ci[j]*inv;
    orr[j] = f2us(nr*grf[j] - ni*gif[j] + brf[j]);
    oii[j] = f2us(nr*gif[j] + ni*grf[j] + bif[j]);
  }
  o_r.x=orr[0]; o_r.y=orr[1]; o_r.z=orr[2]; o_r.w=orr[3];
  o_i.x=oii[0]; o_i.y=oii[1]; o_i.z=oii[2]; o_i.w=oii[3];
  ((ushort4*)(outr + (size_t)row*Dq))[t] = o_r;
  ((ushort4*)(outi + (size_t)row*Dq))[t] = o_i;
}

// ---------------- complex GEMM v7: r4 core + 3-deep counted-vmcnt pipeline (T4) ----------------
// Block: 256 threads (4 waves, 2x2). Tile 64(M) x 64(N), BK=32.
// LDS: 3 rotating buffers x 4 planes x 4KB = 48 KB. Per K-step: issue stage(t+2) ->
// s_waitcnt vmcnt(8) (tiles t+1,t+2 stay in flight; tile t retired) -> s_barrier ->
// compute(t) -> s_barrier. Loads get ~2 compute phases to land; vmcnt NEVER drains
// to 0 in the main loop (T4, m218). Loop unrolled x3 (static buffer indices);
// requires (nk-2)%3 == 0 -- holds for nk in {32,128} (K = 1024/4096).
// EPI: 0 plain bf16; 1 +bias+resid(f32)->f32; 2 +bias+ModReLU->bf16; 3 = 1
// SPLIT3: output scattered to 3 arrays of stride 1024 by n0>>10 (merged QKV).
template<int EPI, bool ROPE, bool SPLIT3>
__global__ __launch_bounds__(256,3) void cgemm16_kernel(
    const unsigned short* __restrict__ Ar, const unsigned short* __restrict__ Ai,
    const unsigned short* __restrict__ Wr, const unsigned short* __restrict__ Wi,
    void* __restrict__ Cr0, void* __restrict__ Ci0,
    void* __restrict__ Cr1, void* __restrict__ Ci1,
    void* __restrict__ Cr2, void* __restrict__ Ci2,
    const float* __restrict__ biasR, const float* __restrict__ biasI,
    const float* __restrict__ resR, const float* __restrict__ resI,
    const float* __restrict__ modb,
    int Ndim, int Kdim)
{
  const int t = threadIdx.x;
  const int w = t >> 6, lane = t & 63;
  const int quad = lane >> 4, l15 = lane & 15;
  const int wr = w >> 1, wc = w & 1;
  const int m0 = blockIdx.x * 64, n0 = blockIdx.y * 64;

  __shared__ __align__(16) unsigned short sAll[3*4*2048];   // 48 KB

  const floatx4 fz = {0.f,0.f,0.f,0.f};
  floatx4 accRR[2][2], accII[2][2], accRI[2][2], accIR[2][2];
  #pragma unroll
  for (int i=0;i<2;++i)
    #pragma unroll
    for (int j=0;j<2;++j){ accRR[i][j]=fz; accII[i][j]=fz; accRI[i][j]=fz; accIR[i][j]=fz; }

  // ---- staging: thread t -> LDS slot t (row t>>2, chunk t&3); logical chunk = (t&3)^((t>>2)&3)
  const int srow = t >> 2;
  const int lc = ((t & 3) ^ ((t >> 2) & 3)) * 8;     // ushort offset within row
  const unsigned short* pAr = Ar + (size_t)(m0 + srow)*Kdim + lc;
  const unsigned short* pAi = Ai + (size_t)(m0 + srow)*Kdim + lc;
  const unsigned short* pWr = Wr + (size_t)(n0 + srow)*Kdim + lc;
  const unsigned short* pWi = Wi + (size_t)(n0 + srow)*Kdim + lc;
  const int dst0 = t * 8;

  // ---- fragment read offsets (ushort idx): row*32 + (quad ^ (row&3))*8
  const int arow0 = wr*32 + l15,       arow1 = arow0 + 16;
  const int wrow0 = wc*16 + l15,       wrow1 = wrow0 + 32;
  const int aoff0 = arow0*32 + ((quad ^ (arow0 & 3))*8);
  const int aoff1 = arow1*32 + ((quad ^ (arow1 & 3))*8);
  const int woff0 = wrow0*32 + ((quad ^ (wrow0 & 3))*8);
  const int woff1 = wrow1*32 + ((quad ^ (wrow1 & 3))*8);

#define STAGEB(B, KOFF) do{                                                \
    gld16(pAr + (KOFF), &sAll[(B)*8192 + dst0]);                           \
    gld16(pAi + (KOFF), &sAll[(B)*8192 + 2048 + dst0]);                    \
    gld16(pWr + (KOFF), &sAll[(B)*8192 + 4096 + dst0]);                    \
    gld16(pWi + (KOFF), &sAll[(B)*8192 + 6144 + dst0]);                    \
  }while(0)

#define COMPUTEB(B) do{                                                    \
    const unsigned short* SA = &sAll[(B)*8192];                            \
    const unsigned short* SB = SA + 2048;                                  \
    const unsigned short* SC = SA + 4096;                                  \
    const unsigned short* SD = SA + 6144;                                  \
    bf16x8 fA0r = *(const bf16x8*)&SA[aoff0];                              \
    bf16x8 fA1r = *(const bf16x8*)&SA[aoff1];                              \
    bf16x8 fA0i = *(const bf16x8*)&SB[aoff0];                              \
    bf16x8 fA1i = *(const bf16x8*)&SB[aoff1];                              \
    bf16x8 fW0r = *(const bf16x8*)&SC[woff0];                              \
    bf16x8 fW1r = *(const bf16x8*)&SC[woff1];                              \
    bf16x8 fW0i = *(const bf16x8*)&SD[woff0];                              \
    bf16x8 fW1i = *(const bf16x8*)&SD[woff1];                              \
    accRR[0][0] = __builtin_amdgcn_mfma_f32_16x16x32_bf16(fA0r, fW0r, accRR[0][0], 0,0,0); \
    accII[0][0] = __builtin_amdgcn_mfma_f32_16x16x32_bf16(fA0i, fW0i, accII[0][0], 0,0,0); \
    accRI[0][0] = __builtin_amdgcn_mfma_f32_16x16x32_bf16(fA0r, fW0i, accRI[0][0], 0,0,0); \
    accIR[0][0] = __builtin_amdgcn_mfma_f32_16x16x32_bf16(fA0i, fW0r, accIR[0][0], 0,0,0); \
    accRR[0][1] = __builtin_amdgcn_mfma_f32_16x16x32_bf16(fA0r, fW1r, accRR[0][1], 0,0,0); \
    accII[0][1] = __builtin_amdgcn_mfma_f32_16x16x32_bf16(fA0i, fW1i, accII[0][1], 0,0,0); \
    accRI[0][1] = __builtin_amdgcn_mfma_f32_16x16x32_bf16(fA0r, fW1i, accRI[0][1], 0,0,0); \
    accIR[0][1] = __builtin_amdgcn_mfma_f32_16x16x32_bf16(fA0i, fW1r, accIR[0][1], 0,0,0); \
    accRR[1][0] = __builtin_amdgcn_mfma_f32_16x16x32_bf16(fA1r, fW0r, accRR[1][0], 0,0,0); \
    accII[1][0] = __builtin_amdgcn_mfma_f32_16x16x32_bf16(fA1i, fW0i, accII[1][0], 0,0,0); \
    accRI[1][0] = __builtin_amdgcn_mfma_f32_16x16x32_bf16(fA1r, fW0i, accRI[1][0], 0,0,0); \
    accIR[1][0] = __builtin_amdgcn_mfma_f32_16x16x32_bf16(fA1i, fW0r, accIR[1][0], 0,0,0); \
    accRR[1][1] = __builtin_amdgcn_mfma_f32_16x16x32_bf16(fA1r, fW1r, accRR[1][1], 0,0,0); \
    accII[1][1] = __builtin_amdgcn_mfma_f32_16x16x32_bf16(fA1i, fW1i, accII[1][1], 0,0,0); \
    accRI[1][1] = __builtin_amdgcn_mfma_f32_16x16x32_bf16(fA1r, fW1i, accRI[1][1], 0,0,0); \
    accIR[1][1] = __builtin_amdgcn_mfma_f32_16x16x32_bf16(fA1i, fW1r, accIR[1][1], 0,0,0); \
  }while(0)

// counted-vmcnt sync: wait until <=N vmem ops outstanding, then barrier.
// memory-clobber fences keep LDS reads from hoisting above the barrier.
#define SYNC_VM(N) do{                                                     \
    asm volatile("s_waitcnt vmcnt(" #N ")" ::: "memory");                  \
    __builtin_amdgcn_s_barrier();                                          \
    asm volatile("" ::: "memory");                                         \
  }while(0)
#define SYNC_BAR() do{                                                     \
    asm volatile("" ::: "memory");                                         \
    __builtin_amdgcn_s_barrier();                                          \
    asm volatile("" ::: "memory");                                         \
  }while(0)

  const int nk = Kdim >> 5;          // 32 or 128; (nk-2)%3 == 0 required
  STAGEB(0, 0);
  STAGEB(1, 32);
  for (int kk=0; kk<nk-2; kk+=3){
    STAGEB(2, (kk+2)*32);  SYNC_VM(8);  COMPUTEB(0);  SYNC_BAR();
    STAGEB(0, (kk+3)*32);  SYNC_VM(8);  COMPUTEB(1);  SYNC_BAR();
    STAGEB(1, (kk+4)*32);  SYNC_VM(8);  COMPUTEB(2);  SYNC_BAR();
  }
  // tiles nk-2 (buf 0, since (nk-2)%3==0) and nk-1 (buf 1)
  SYNC_VM(4);  COMPUTEB(0);
  SYNC_VM(0);  COMPUTEB(1);
#undef STAGEB
#undef COMPUTEB
#undef SYNC_VM
#undef SYNC_BAR

  // ---- epilogue: C 16x16 layout: col = l15, row = quad*4 + r ----
  float cr[2][2][4], ci[2][2][4];
  #pragma unroll
  for (int mf=0; mf<2; ++mf)
    #pragma unroll
    for (int nf=0; nf<2; ++nf)
      #pragma unroll
      for (int r=0;r<4;++r){
        cr[mf][nf][r] = accRR[mf][nf][r] - accII[mf][nf][r];
        ci[mf][nf][r] = accRI[mf][nf][r] + accIR[mf][nf][r];
      }

  // RoPE: head = this 64-col block; d = wc*16 + nfi*32 + l15, pair (d, d+32) = (nf0, nf1)
  const bool doRope = ROPE && (!SPLIT3 || (n0 < 2048));
  if (doRope){
    const float invf = powf(10000.0f, -(float)(wc*16 + l15) * (1.0f/32.0f));
    #pragma unroll
    for (int mf=0; mf<2; ++mf)
      #pragma unroll
      for (int r=0;r<4;++r){
        const int gm = m0 + wr*32 + mf*16 + quad*4 + r;
        float s, c;
        sincosf((float)(gm & (Lq-1)) * invf, &s, &c);
        float xr_ = cr[mf][0][r], yr_ = cr[mf][1][r];
        cr[mf][0][r] = xr_*c - yr_*s;  cr[mf][1][r] = yr_*c + xr_*s;
        float xi_ = ci[mf][0][r], yi_ = ci[mf][1][r];
        ci[mf][0][r] = xi_*c - yi_*s;  ci[mf][1][r] = yi_*c + xi_*s;
      }
  }

  unsigned short *oR16 = nullptr, *oI16 = nullptr;
  float *oR32 = nullptr, *oI32 = nullptr;
  int ncol0, Nst;
  if (SPLIT3){
    const int aid = n0 >> 10;
    void* vr = (aid==0) ? Cr0 : ((aid==1) ? Cr1 : Cr2);
    void* vi = (aid==0) ? Ci0 : ((aid==1) ? Ci1 : Ci2);
    oR16 = (unsigned short*)vr; oI16 = (unsigned short*)vi;
    ncol0 = n0 & 1023; Nst = 1024;
  } else {
    oR16 = (unsigned short*)Cr0; oI16 = (unsigned short*)Ci0;
    oR32 = (float*)Cr0;          oI32 = (float*)Ci0;
    ncol0 = n0; Nst = Ndim;
  }

  #pragma unroll
  for (int nf=0; nf<2; ++nf){
    const int gn = n0 + wc*16 + nf*32 + l15;      // full-N index (bias/modb)
    const int cn = ncol0 + wc*16 + nf*32 + l15;   // output-array col
    float bR = 0.f, bI = 0.f, mb = 0.f;
    if (EPI >= 1){ bR = biasR[gn]; bI = biasI[gn]; }
    if (EPI == 2){ mb = modb[gn]; }
    #pragma unroll
    for (int mf=0; mf<2; ++mf)
      #pragma unroll
      for (int r=0;r<4;++r){
        const int gm = m0 + wr*32 + mf*16 + quad*4 + r;
        const size_t idx = (size_t)gm*Nst + cn;
        float vr_ = cr[mf][nf][r] + bR, vi_ = ci[mf][nf][r] + bI;
        if (EPI == 1 || EPI == 3){ vr_ += resR[idx]; vi_ += resI[idx]; }
        if (EPI == 2){
          float mag = sqrtf(vr_*vr_ + vi_*vi_);
          float safe = (mag > 0.f) ? mag : 1.0f;
          float act = fmaxf(mag + mb, 0.f);
          float sc = act / safe;
          vr_ *= sc; vi_ *= sc;
        }
        if (EPI == 0 || EPI == 2){
          oR16[idx] = f2us(vr_);
          oI16[idx] = f2us(vi_);
        } else {
          oR32[idx] = vr_;
          oI32[idx] = vi_;
        }
      }
  }
}

// ---------------- V transpose: V[b,l,h*64+d] -> VT[(b*16+h)*64+d][l] ----------------
__global__ __launch_bounds__(256) void vtrans_kernel(
    const unsigned short* __restrict__ Vr, const unsigned short* __restrict__ Vi,
    unsigned short* __restrict__ VTr, unsigned short* __restrict__ VTi)
{
  const int lt = blockIdx.x;      // 0..15 (L tile)
  const int bh = blockIdx.y;      // 0..31
  const int h = bh & (Hq-1), b = bh >> 4;
  const int t = threadIdx.x;
  __shared__ unsigned short sTr[64*65], sTi[64*65];

  const int row = t >> 2;          // l-local 0..63
  const int dc  = (t & 3) * 16;    // d chunk
  const size_t g = ((size_t)(b*Lq) + lt*64 + row)*Dq + h*HDq + dc;
  uint4 a0 = *(const uint4*)(Vr + g);
  uint4 a1 = *(const uint4*)(Vr + g + 8);
  uint4 b0 = *(const uint4*)(Vi + g);
  uint4 b1 = *(const uint4*)(Vi + g + 8);
  const unsigned short* pa0 = (const unsigned short*)&a0;
  const unsigned short* pa1 = (const unsigned short*)&a1;
  const unsigned short* pb0 = (const unsigned short*)&b0;
  const unsigned short* pb1 = (const unsigned short*)&b1;
  #pragma unroll
  for (int e=0;e<8;++e){
    sTr[(dc+e)*65 + row]   = pa0[e];
    sTr[(dc+8+e)*65 + row] = pa1[e];
    sTi[(dc+e)*65 + row]   = pb0[e];
    sTi[(dc+8+e)*65 + row] = pb1[e];
  }
  __syncthreads();
  const int d  = t >> 2;
  const int lcx = (t & 3) * 16;
  unsigned short bufr[16], bufi[16];
  #pragma unroll
  for (int e=0;e<16;++e){
    bufr[e] = sTr[d*65 + lcx + e];
    bufi[e] = sTi[d*65 + lcx + e];
  }
  const size_t og = ((size_t)bh*HDq + d)*Lq + lt*64 + lcx;
  *(uint4*)(VTr + og)     = *(const uint4*)&bufr[0];
  *(uint4*)(VTr + og + 8) = *(const uint4*)&bufr[8];
  *(uint4*)(VTi + og)     = *(const uint4*)&bufi[0];
  *(uint4*)(VTi + og + 8) = *(const uint4*)&bufi[8];
}

// ---------------- flash attention: 64x64 tiles, MFMA, online softmax ----------------
__device__ __forceinline__ int swz(int v){ return v ^ ((v >> 4) & 7); }

__global__ __launch_bounds__(256,2) void fattn_kernel(
    const unsigned short* __restrict__ Qr, const unsigned short* __restrict__ Qi,
    const unsigned short* __restrict__ Kr, const unsigned short* __restrict__ Ki,
    const unsigned short* __restrict__ VTr, const unsigned short* __restrict__ VTi,
    unsigned short* __restrict__ Or, unsigned short* __restrict__ Oi)
{
  const int qt = (int)(gridDim.x - 1 - blockIdx.x);   // big tiles dispatch first
  const int bh = blockIdx.y;
  const int h = bh & (Hq-1), b = bh >> 4;
  const int t = threadIdx.x;
  const int w = t >> 6, lane = t & 63;
  const int quad = lane >> 4, l15 = lane & 15;

  __shared__ __align__(16) unsigned short sKr[4096], sKi[4096], sVr[4096], sVi[4096];
  __shared__ __align__(16) unsigned short sP[64*72];

  const size_t qbase = ((size_t)(b*Lq) + qt*64 + w*16 + l15)*Dq + h*HDq;
  bf16x8 qr_lo = *(const bf16x8*)(Qr + qbase + quad*8);
  bf16x8 qr_hi = *(const bf16x8*)(Qr + qbase + 32 + quad*8);
  bf16x8 qi_lo = *(const bf16x8*)(Qi + qbase + quad*8);
  bf16x8 qi_hi = *(const bf16x8*)(Qi + qbase + 32 + quad*8);

  const floatx4 fzero = {0.f,0.f,0.f,0.f};
  floatx4 aOr[4], aOi[4];
  #pragma unroll
  for (int i=0;i<4;++i){ aOr[i]=fzero; aOi[i]=fzero; }
  float m_run[4] = {-1e30f,-1e30f,-1e30f,-1e30f};
  float l_run[4] = {0.f,0.f,0.f,0.f};

  const int srow = t >> 2;
  const int sns  = srow >> 4;
  const int sl15 = srow & 15;
  const int q8   = (t & 3) * 2;
  const int dstA = sns*1024 + swz(q8*16 + sl15)*8;
  const int dstB = sns*1024 + swz((q8+1)*16 + sl15)*8;

  const int rd0 = swz(quad*16 + l15)*8;
  const int rd1 = swz((4+quad)*16 + l15)*8;

  for (int kt = 0; kt <= qt; ++kt){
    const size_t kg = ((size_t)(b*Lq) + kt*64 + srow)*Dq + h*HDq + q8*8;
    uint4 ka = *(const uint4*)(Kr + kg);
    uint4 kb = *(const uint4*)(Kr + kg + 8);
    uint4 kc = *(const uint4*)(Ki + kg);
    uint4 kd = *(const uint4*)(Ki + kg + 8);
    const size_t vg = ((size_t)bh*HDq + srow)*Lq + kt*64 + q8*8;
    uint4 va = *(const uint4*)(VTr + vg);
    uint4 vb = *(const uint4*)(VTr + vg + 8);
    uint4 vc = *(const uint4*)(VTi + vg);
    uint4 vd = *(const uint4*)(VTi + vg + 8);
    __syncthreads();
    *(uint4*)&sKr[dstA] = ka;  *(uint4*)&sKr[dstB] = kb;
    *(uint4*)&sKi[dstA] = kc;  *(uint4*)&sKi[dstB] = kd;
    *(uint4*)&sVr[dstA] = va;  *(uint4*)&sVr[dstB] = vb;
    *(uint4*)&sVi[dstA] = vc;  *(uint4*)&sVi[dstB] = vd;
    __syncthreads();

    floatx4 sc[4];
    #pragma unroll
    for (int ns=0; ns<4; ++ns){
      floatx4 x = fzero;
      x = __builtin_amdgcn_mfma_f32_16x16x32_bf16(qr_lo, *(const bf16x8*)&sKr[ns*1024 + rd0], x, 0,0,0);
      x = __builtin_amdgcn_mfma_f32_16x16x32_bf16(qr_hi, *(const bf16x8*)&sKr[ns*1024 + rd1], x, 0,0,0);
      x = __builtin_amdgcn_mfma_f32_16x16x32_bf16(qi_lo, *(const bf16x8*)&sKi[ns*1024 + rd0], x, 0,0,0);
      x = __builtin_amdgcn_mfma_f32_16x16x32_bf16(qi_hi, *(const bf16x8*)&sKi[ns*1024 + rd1], x, 0,0,0);
      sc[ns] = x;
    }

    const bool diag = (kt == qt);
    float rmax[4] = {-1e30f,-1e30f,-1e30f,-1e30f};
    #pragma unroll
    for (int ns=0; ns<4; ++ns){
      #pragma unroll
      for (int r=0; r<4; ++r){
        float s = sc[ns][r] * 0.125f;
        if (diag && (ns*16 + l15 > w*16 + quad*4 + r)) s = -1e30f;
        sc[ns][r] = s;
        rmax[r] = fmaxf(rmax[r], s);
      }
    }
    #pragma unroll
    for (int off=1; off<16; off<<=1){
      #pragma unroll
      for (int r=0; r<4; ++r) rmax[r] = fmaxf(rmax[r], __shfl_xor(rmax[r], off, 64));
    }

    float alpha[4], rsum[4];
    #pragma unroll
    for (int r=0; r<4; ++r){
      float mn = fmaxf(m_run[r], rmax[r]);
      alpha[r] = __expf(m_run[r] - mn);
      m_run[r] = mn;
      rsum[r] = 0.f;
    }
    #pragma unroll
    for (int ns=0; ns<4; ++ns){
      #pragma unroll
      for (int r=0; r<4; ++r){
        float p = __expf(sc[ns][r] - m_run[r]);
        rsum[r] += p;
        sP[(w*16 + quad*4 + r)*72 + ns*16 + l15] = f2us(p);
      }
    }
    #pragma unroll
    for (int off=1; off<16; off<<=1){
      #pragma unroll
      for (int r=0; r<4; ++r) rsum[r] += __shfl_xor(rsum[r], off, 64);
    }
    #pragma unroll
    for (int r=0; r<4; ++r) l_run[r] = l_run[r]*alpha[r] + rsum[r];
    #pragma unroll
    for (int ds=0; ds<4; ++ds)
      #pragma unroll
      for (int r=0; r<4; ++r){ aOr[ds][r] *= alpha[r]; aOi[ds][r] *= alpha[r]; }

    #pragma unroll
    for (int step=0; step<2; ++step){
      bf16x8 pf = *(const bf16x8*)&sP[(w*16 + l15)*72 + step*32 + quad*8];
      const int ro = (step==0) ? rd0 : rd1;
      #pragma unroll
      for (int ds=0; ds<4; ++ds){
        aOr[ds] = __builtin_amdgcn_mfma_f32_16x16x32_bf16(pf, *(const bf16x8*)&sVr[ds*1024 + ro], aOr[ds], 0,0,0);
        aOi[ds] = __builtin_amdgcn_mfma_f32_16x16x32_bf16(pf, *(const bf16x8*)&sVi[ds*1024 + ro], aOi[ds], 0,0,0);
      }
    }
  }

  #pragma unroll
  for (int r=0; r<4; ++r){
    const float il = 1.0f / l_run[r];
    const size_t ob = ((size_t)(b*Lq) + qt*64 + w*16 + quad*4 + r)*Dq + h*HDq;
    #pragma unroll
    for (int ds=0; ds<4; ++ds){
      Or[ob + ds*16 + l15] = f2us(aOr[ds][r] * il);
      Oi[ob + ds*16 + l15] = f2us(aOi[ds][r] * il);
    }
  }
}

// ---------------- launch ----------------
extern "C" void kernel_launch(void* const* d_in, const int* in_sizes, int n_in,
                              void* d_out, int out_size, void* d_ws, size_t ws_size,
                              hipStream_t stream)
{
  const float* x_r    = (const float*)d_in[0];
  const float* x_i    = (const float*)d_in[1];
  const float* Wq_r   = (const float*)d_in[2];
  const float* Wq_i   = (const float*)d_in[3];
  const float* Wk_r   = (const float*)d_in[4];
  const float* Wk_i   = (const float*)d_in[5];
  const float* Wv_r   = (const float*)d_in[6];
  const float* Wv_i   = (const float*)d_in[7];
  const float* Wo_r   = (const float*)d_in[8];
  const float* Wo_i   = (const float*)d_in[9];
  const float* bo_r   = (const float*)d_in[10];
  const float* bo_i   = (const float*)d_in[11];
  const float* ln1_gr = (const float*)d_in[12];
  const float* ln1_gi = (const float*)d_in[13];
  const float* ln1_br = (const float*)d_in[14];
  const float* ln1_bi = (const float*)d_in[15];
  const float* ln2_gr = (const float*)d_in[16];
  const float* ln2_gi = (const float*)d_in[17];
  const float* ln2_br = (const float*)d_in[18];
  const float* ln2_bi = (const float*)d_in[19];
  const float* W1_r   = (const float*)d_in[20];
  const float* W1_i   = (const float*)d_in[21];
  const float* b1_r   = (const float*)d_in[22];
  const float* b1_i   = (const float*)d_in[23];
  const float* W2_r   = (const float*)d_in[24];
  const float* W2_i   = (const float*)d_in[25];
  const float* b2_r   = (const float*)d_in[26];
  const float* b2_i   = (const float*)d_in[27];
  const float* mod_b  = (const float*)d_in[28];

  char* wsb = (char*)d_ws;
  const size_t MB = 1024*1024;
  // --- weights, bf16: 0..48 MB ---
  // QKV weights stacked [3072][1024] for the merged projection GEMM
  unsigned short* bQKV_r = (unsigned short*)(wsb + 0*MB);   // Wq_r @0, Wk_r @2MB, Wv_r @4MB
  unsigned short* bQKV_i = (unsigned short*)(wsb + 6*MB);   // Wq_i @6, Wk_i @8, Wv_i @10
  unsigned short* bWo_r = (unsigned short*)(wsb + 12*MB);
  unsigned short* bWo_i = (unsigned short*)(wsb + 14*MB);
  unsigned short* bW1_r = (unsigned short*)(wsb + 16*MB);
  unsigned short* bW1_i = (unsigned short*)(wsb + 24*MB);
  unsigned short* bW2_r = (unsigned short*)(wsb + 32*MB);
  unsigned short* bW2_i = (unsigned short*)(wsb + 40*MB);
  // --- activations: 48..96 MB ---
  unsigned short* hr  = (unsigned short*)(wsb + 48*MB);
  unsigned short* hi_ = (unsigned short*)(wsb + 52*MB);
  unsigned short* Qr  = (unsigned short*)(wsb + 56*MB);
  unsigned short* Qi  = (unsigned short*)(wsb + 60*MB);
  unsigned short* Kr  = (unsigned short*)(wsb + 64*MB);
  unsigned short* Ki  = (unsigned short*)(wsb + 68*MB);
  unsigned short* Vr  = (unsigned short*)(wsb + 72*MB);
  unsigned short* Vi  = (unsigned short*)(wsb + 76*MB);
  unsigned short* VTr = (unsigned short*)(wsb + 80*MB);
  unsigned short* VTi = (unsigned short*)(wsb + 84*MB);
  unsigned short* Or  = hr;                               // hr/hi dead after QKV gemm
  unsigned short* Oi  = hi_;
  unsigned short* h2r = Qr;                               // Q dead after attn
  unsigned short* h2i = Qi;
  unsigned short* fr  = (unsigned short*)(wsb + 64*MB);   // over K/V (dead after attn)
  unsigned short* fi  = (unsigned short*)(wsb + 80*MB);   // over VT (dead after attn)

  float* outR = (float*)d_out;
  float* outI = outR + (size_t)Mq*Dq;

  const dim3 blk(256);

  const int nDD = Dq*Dq;
  const int nDH = Dq*HIDq;
  cvt4_kernel<<<dim3(nDD/2048, 4), blk, 0, stream>>>(Wq_r, Wk_r, Wv_r, Wo_r,
      bQKV_r, bQKV_r + (size_t)nDD, bQKV_r + (size_t)2*nDD, bWo_r, nDD);
  cvt4_kernel<<<dim3(nDD/2048, 4), blk, 0, stream>>>(Wq_i, Wk_i, Wv_i, Wo_i,
      bQKV_i, bQKV_i + (size_t)nDD, bQKV_i + (size_t)2*nDD, bWo_i, nDD);
  cvt4_kernel<<<dim3(nDH/2048, 4), blk, 0, stream>>>(W1_r, W1_i, W2_r, W2_i,
      bW1_r, bW1_i, bW2_r, bW2_i, nDH);

  // 1. ln1
  cln_kernel<<<Mq, blk, 0, stream>>>(x_r, x_i, ln1_gr, ln1_gi, ln1_br, ln1_bi, hr, hi_);
  // 2. merged Q,K,V projection (RoPE fused on Q,K; scatter to 3 arrays)
  cgemm16_kernel<0,true,true><<<dim3(Mq/64, 3072/64), blk, 0, stream>>>(
      hr, hi_, bQKV_r, bQKV_i,
      Qr, Qi, Kr, Ki, Vr, Vi,
      nullptr, nullptr, nullptr, nullptr, nullptr, 3072, Dq);
  // 2b. V transpose for PV fragments
  vtrans_kernel<<<dim3(16, 32), blk, 0, stream>>>(Vr, Vi, VTr, VTi);
  // 3. flash attention (writes O over hr/hi)
  fattn_kernel<<<dim3(16, 32), blk, 0, stream>>>(Qr, Qi, Kr, Ki, VTr, VTi, Or, Oi);
  // 4. Wo + bias + residual(x) -> d_out (f32)
  cgemm16_kernel<1,false,false><<<dim3(Mq/64, Dq/64), blk, 0, stream>>>(
      Or, Oi, bWo_r, bWo_i, outR, outI, nullptr, nullptr, nullptr, nullptr,
      bo_r, bo_i, x_r, x_i, nullptr, Dq, Dq);
  // 5. ln2
  cln_kernel<<<Mq, blk, 0, stream>>>(outR, outI, ln2_gr, ln2_gi, ln2_br, ln2_bi, h2r, h2i);
  // 6. W1 + bias + ModReLU -> f
  cgemm16_kernel<2,false,false><<<dim3(Mq/64, HIDq/64), blk, 0, stream>>>(
      h2r, h2i, bW1_r, bW1_i, fr, fi, nullptr, nullptr, nullptr, nullptr,
      b1_r, b1_i, nullptr, nullptr, mod_b, HIDq, Dq);
  // 7. W2 + bias + residual(d_out) -> d_out in-place (f32)
  cgemm16_kernel<3,false,false><<<dim3(Mq/64, Dq/64), blk, 0, stream>>>(
      fr, fi, bW2_r, bW2_i, outR, outI, nullptr, nullptr, nullptr, nullptr,
      b2_r, b2_i, outR, outI, nullptr, Dq, HIDq);
}

// Round 9
// 487.452 us; speedup vs baseline: 1.1134x; 1.0013x over previous
//
#include <hip/hip_runtime.h>

#define Bq 2
#define Lq 1024
#define Dq 1024
#define Hq 16
#define HDq 64
#define HIDq 4096
#define Mq (Bq*Lq)   // 2048

typedef __bf16 bf16x8 __attribute__((ext_vector_type(8)));
typedef float floatx4 __attribute__((ext_vector_type(4)));

__device__ __forceinline__ unsigned short f2us(float f){
  unsigned u = __builtin_bit_cast(unsigned, f);
  u = u + 0x7fffu + ((u >> 16) & 1u);      // RNE to bf16
  return (unsigned short)(u >> 16);
}

// async global->LDS, 16B per lane (dest must be linear: wave base + lane*16)
__device__ __forceinline__ void gld16(const unsigned short* g, unsigned short* l){
  __builtin_amdgcn_global_load_lds(
      (const __attribute__((address_space(1))) unsigned int*)g,
      (__attribute__((address_space(3))) unsigned int*)l, 16, 0, 0);
}

// ---------------- f32 -> bf16 conversion (weights), 4 arrays per launch ----------------
__global__ __launch_bounds__(256) void cvt4_kernel(
    const float* __restrict__ s0, const float* __restrict__ s1,
    const float* __restrict__ s2, const float* __restrict__ s3,
    unsigned short* __restrict__ d0, unsigned short* __restrict__ d1,
    unsigned short* __restrict__ d2, unsigned short* __restrict__ d3,
    int n)
{
  const int a = blockIdx.y;
  const float* s = (a==0) ? s0 : (a==1) ? s1 : (a==2) ? s2 : s3;
  unsigned short* d = (a==0) ? d0 : (a==1) ? d1 : (a==2) ? d2 : d3;
  const int i = (blockIdx.x * 256 + threadIdx.x) * 8;
  if (i >= n) return;
  float4 v0 = ((const float4*)(s + i))[0];
  float4 v1 = ((const float4*)(s + i))[1];
  ushort4 o0, o1;
  o0.x=f2us(v0.x); o0.y=f2us(v0.y); o0.z=f2us(v0.z); o0.w=f2us(v0.w);
  o1.x=f2us(v1.x); o1.y=f2us(v1.y); o1.z=f2us(v1.z); o1.w=f2us(v1.w);
  ((ushort4*)(d + i))[0] = o0;
  ((ushort4*)(d + i))[1] = o1;
}

// ---------------- complex LayerNorm: f32 in, bf16 out; one block per row ----------------
__global__ __launch_bounds__(256) void cln_kernel(
    const float* __restrict__ xr, const float* __restrict__ xi,
    const float* __restrict__ gr, const float* __restrict__ gi,
    const float* __restrict__ br, const float* __restrict__ bi,
    unsigned short* __restrict__ outr, unsigned short* __restrict__ outi)
{
  const int row = blockIdx.x;
  const int t = threadIdx.x;
  const int lane = t & 63, wv = t >> 6;
  __shared__ float sred[8];

  float4 v4r = ((const float4*)(xr + (size_t)row*Dq))[t];
  float4 v4i = ((const float4*)(xi + (size_t)row*Dq))[t];
  float vr[4] = {v4r.x, v4r.y, v4r.z, v4r.w};
  float vi[4] = {v4i.x, v4i.y, v4i.z, v4i.w};
  float sr = vr[0]+vr[1]+vr[2]+vr[3];
  float si = vi[0]+vi[1]+vi[2]+vi[3];
  #pragma unroll
  for (int o=32;o>0;o>>=1){ sr += __shfl_down(sr,o,64); si += __shfl_down(si,o,64); }
  if (lane==0){ sred[wv]=sr; sred[4+wv]=si; }
  __syncthreads();
  float mr = (sred[0]+sred[1]+sred[2]+sred[3]) * (1.0f/Dq);
  float mi = (sred[4]+sred[5]+sred[6]+sred[7]) * (1.0f/Dq);
  float cr[4], ci[4], vs = 0.f;
  #pragma unroll
  for (int j=0;j<4;++j){ cr[j]=vr[j]-mr; ci[j]=vi[j]-mi; vs += cr[j]*cr[j]+ci[j]*ci[j]; }
  #pragma unroll
  for (int o=32;o>0;o>>=1) vs += __shfl_down(vs,o,64);
  __syncthreads();
  if (lane==0) sred[wv]=vs;
  __syncthreads();
  float var = (sred[0]+sred[1]+sred[2]+sred[3]) * (1.0f/Dq);
  float inv = rsqrtf(var + 1e-6f);

  float4 g4r = ((const float4*)gr)[t];
  float4 g4i = ((const float4*)gi)[t];
  float4 b4r = ((const float4*)br)[t];
  float4 b4i = ((const float4*)bi)[t];
  float grf[4] = {g4r.x,g4r.y,g4r.z,g4r.w};
  float gif[4] = {g4i.x,g4i.y,g4i.z,g4i.w};
  float brf[4] = {b4r.x,b4r.y,b4r.z,b4r.w};
  float bif[4] = {b4i.x,b4i.y,b4i.z,b4i.w};
  ushort4 o_r, o_i;
  unsigned short orr[4], oii[4];
  #pragma unroll
  for (int j=0;j<4;++j){
    float nr = cr[j]*inv, ni = ci[j]*inv;
    orr[j] = f2us(nr*grf[j] - ni*gif[j] + brf[j]);
    oii[j] = f2us(nr*gif[j] + ni*grf[j] + bif[j]);
  }
  o_r.x=orr[0]; o_r.y=orr[1]; o_r.z=orr[2]; o_r.w=orr[3];
  o_i.x=oii[0]; o_i.y=oii[1]; o_i.z=oii[2]; o_i.w=oii[3];
  ((ushort4*)(outr + (size_t)row*Dq))[t] = o_r;
  ((ushort4*)(outi + (size_t)row*Dq))[t] = o_i;
}

// ---------------- complex GEMM v8: r8 pipeline + corrected bank swizzle ----------------
// Block: 256 threads (4 waves, 2x2). Tile 64(M) x 64(N), BK=32.
// LDS: 3 rotating buffers x 4 planes x 4KB = 48 KB; counted vmcnt(8) (T4), never 0
// in the main loop. Loop unrolled x3; requires (nk-2)%3 == 0 (nk in {32,128}).
// SWIZZLE FIX (r9): physical chunk = kchunk ^ ((row>>1)&3)  [was row&3].
// Row stride 64B = 16 banks, so base bank depends only on row&1; the old XOR left
// rows {r,r+4,r+8,r+12} (same parity, same chunk) on the same 4 banks -> 4-way
// conflict on every ds_read_b128 (the measured 8.4e6). XOR-ing row bits 1-2 gives
// same-parity rows distinct chunks -> 2-way max (free, m136).
// EPI: 0 plain bf16; 1 +bias+resid(f32)->f32; 2 +bias+ModReLU->bf16; 3 = 1
// SPLIT3: output scattered to 3 arrays of stride 1024 by n0>>10 (merged QKV).
template<int EPI, bool ROPE, bool SPLIT3>
__global__ __launch_bounds__(256,3) void cgemm16_kernel(
    const unsigned short* __restrict__ Ar, const unsigned short* __restrict__ Ai,
    const unsigned short* __restrict__ Wr, const unsigned short* __restrict__ Wi,
    void* __restrict__ Cr0, void* __restrict__ Ci0,
    void* __restrict__ Cr1, void* __restrict__ Ci1,
    void* __restrict__ Cr2, void* __restrict__ Ci2,
    const float* __restrict__ biasR, const float* __restrict__ biasI,
    const float* __restrict__ resR, const float* __restrict__ resI,
    const float* __restrict__ modb,
    int Ndim, int Kdim)
{
  const int t = threadIdx.x;
  const int w = t >> 6, lane = t & 63;
  const int quad = lane >> 4, l15 = lane & 15;
  const int wr = w >> 1, wc = w & 1;
  const int m0 = blockIdx.x * 64, n0 = blockIdx.y * 64;

  __shared__ __align__(16) unsigned short sAll[3*4*2048];   // 48 KB

  const floatx4 fz = {0.f,0.f,0.f,0.f};
  floatx4 accRR[2][2], accII[2][2], accRI[2][2], accIR[2][2];
  #pragma unroll
  for (int i=0;i<2;++i)
    #pragma unroll
    for (int j=0;j<2;++j){ accRR[i][j]=fz; accII[i][j]=fz; accRI[i][j]=fz; accIR[i][j]=fz; }

  // ---- staging: thread t -> LDS slot t (row t>>2, phys chunk t&3);
  // logical kchunk = (t&3) ^ ((row>>1)&3) = (t&3) ^ ((t>>3)&3)
  const int srow = t >> 2;
  const int lc = ((t & 3) ^ ((t >> 3) & 3)) * 8;     // ushort offset within row
  const unsigned short* pAr = Ar + (size_t)(m0 + srow)*Kdim + lc;
  const unsigned short* pAi = Ai + (size_t)(m0 + srow)*Kdim + lc;
  const unsigned short* pWr = Wr + (size_t)(n0 + srow)*Kdim + lc;
  const unsigned short* pWi = Wi + (size_t)(n0 + srow)*Kdim + lc;
  const int dst0 = t * 8;

  // ---- fragment read offsets (ushort idx): row*32 + ((quad ^ ((row>>1)&3))*8)
  const int arow0 = wr*32 + l15,       arow1 = arow0 + 16;
  const int wrow0 = wc*16 + l15,       wrow1 = wrow0 + 32;
  const int aoff0 = arow0*32 + ((quad ^ ((arow0 >> 1) & 3))*8);
  const int aoff1 = arow1*32 + ((quad ^ ((arow1 >> 1) & 3))*8);
  const int woff0 = wrow0*32 + ((quad ^ ((wrow0 >> 1) & 3))*8);
  const int woff1 = wrow1*32 + ((quad ^ ((wrow1 >> 1) & 3))*8);

#define STAGEB(B, KOFF) do{                                                \
    gld16(pAr + (KOFF), &sAll[(B)*8192 + dst0]);                           \
    gld16(pAi + (KOFF), &sAll[(B)*8192 + 2048 + dst0]);                    \
    gld16(pWr + (KOFF), &sAll[(B)*8192 + 4096 + dst0]);                    \
    gld16(pWi + (KOFF), &sAll[(B)*8192 + 6144 + dst0]);                    \
  }while(0)

#define COMPUTEB(B) do{                                                    \
    const unsigned short* SA = &sAll[(B)*8192];                            \
    const unsigned short* SB = SA + 2048;                                  \
    const unsigned short* SC = SA + 4096;                                  \
    const unsigned short* SD = SA + 6144;                                  \
    bf16x8 fA0r = *(const bf16x8*)&SA[aoff0];                              \
    bf16x8 fA1r = *(const bf16x8*)&SA[aoff1];                              \
    bf16x8 fA0i = *(const bf16x8*)&SB[aoff0];                              \
    bf16x8 fA1i = *(const bf16x8*)&SB[aoff1];                              \
    bf16x8 fW0r = *(const bf16x8*)&SC[woff0];                              \
    bf16x8 fW1r = *(const bf16x8*)&SC[woff1];                              \
    bf16x8 fW0i = *(const bf16x8*)&SD[woff0];                              \
    bf16x8 fW1i = *(const bf16x8*)&SD[woff1];                              \
    accRR[0][0] = __builtin_amdgcn_mfma_f32_16x16x32_bf16(fA0r, fW0r, accRR[0][0], 0,0,0); \
    accII[0][0] = __builtin_amdgcn_mfma_f32_16x16x32_bf16(fA0i, fW0i, accII[0][0], 0,0,0); \
    accRI[0][0] = __builtin_amdgcn_mfma_f32_16x16x32_bf16(fA0r, fW0i, accRI[0][0], 0,0,0); \
    accIR[0][0] = __builtin_amdgcn_mfma_f32_16x16x32_bf16(fA0i, fW0r, accIR[0][0], 0,0,0); \
    accRR[0][1] = __builtin_amdgcn_mfma_f32_16x16x32_bf16(fA0r, fW1r, accRR[0][1], 0,0,0); \
    accII[0][1] = __builtin_amdgcn_mfma_f32_16x16x32_bf16(fA0i, fW1i, accII[0][1], 0,0,0); \
    accRI[0][1] = __builtin_amdgcn_mfma_f32_16x16x32_bf16(fA0r, fW1i, accRI[0][1], 0,0,0); \
    accIR[0][1] = __builtin_amdgcn_mfma_f32_16x16x32_bf16(fA0i, fW1r, accIR[0][1], 0,0,0); \
    accRR[1][0] = __builtin_amdgcn_mfma_f32_16x16x32_bf16(fA1r, fW0r, accRR[1][0], 0,0,0); \
    accII[1][0] = __builtin_amdgcn_mfma_f32_16x16x32_bf16(fA1i, fW0i, accII[1][0], 0,0,0); \
    accRI[1][0] = __builtin_amdgcn_mfma_f32_16x16x32_bf16(fA1r, fW0i, accRI[1][0], 0,0,0); \
    accIR[1][0] = __builtin_amdgcn_mfma_f32_16x16x32_bf16(fA1i, fW0r, accIR[1][0], 0,0,0); \
    accRR[1][1] = __builtin_amdgcn_mfma_f32_16x16x32_bf16(fA1r, fW1r, accRR[1][1], 0,0,0); \
    accII[1][1] = __builtin_amdgcn_mfma_f32_16x16x32_bf16(fA1i, fW1i, accII[1][1], 0,0,0); \
    accRI[1][1] = __builtin_amdgcn_mfma_f32_16x16x32_bf16(fA1r, fW1i, accRI[1][1], 0,0,0); \
    accIR[1][1] = __builtin_amdgcn_mfma_f32_16x16x32_bf16(fA1i, fW1r, accIR[1][1], 0,0,0); \
  }while(0)

// counted-vmcnt sync: wait until <=N vmem ops outstanding, then barrier.
// memory-clobber fences keep LDS reads from hoisting above the barrier.
#define SYNC_VM(N) do{                                                     \
    asm volatile("s_waitcnt vmcnt(" #N ")" ::: "memory");                  \
    __builtin_amdgcn_s_barrier();                                          \
    asm volatile("" ::: "memory");                                         \
  }while(0)
#define SYNC_BAR() do{                                                     \
    asm volatile("" ::: "memory");                                         \
    __builtin_amdgcn_s_barrier();                                          \
    asm volatile("" ::: "memory");                                         \
  }while(0)

  const int nk = Kdim >> 5;          // 32 or 128; (nk-2)%3 == 0 required
  STAGEB(0, 0);
  STAGEB(1, 32);
  for (int kk=0; kk<nk-2; kk+=3){
    STAGEB(2, (kk+2)*32);  SYNC_VM(8);  COMPUTEB(0);  SYNC_BAR();
    STAGEB(0, (kk+3)*32);  SYNC_VM(8);  COMPUTEB(1);  SYNC_BAR();
    STAGEB(1, (kk+4)*32);  SYNC_VM(8);  COMPUTEB(2);  SYNC_BAR();
  }
  // tiles nk-2 (buf 0, since (nk-2)%3==0) and nk-1 (buf 1)
  SYNC_VM(4);  COMPUTEB(0);
  SYNC_VM(0);  COMPUTEB(1);
#undef STAGEB
#undef COMPUTEB
#undef SYNC_VM
#undef SYNC_BAR

  // ---- epilogue: C 16x16 layout: col = l15, row = quad*4 + r ----
  float cr[2][2][4], ci[2][2][4];
  #pragma unroll
  for (int mf=0; mf<2; ++mf)
    #pragma unroll
    for (int nf=0; nf<2; ++nf)
      #pragma unroll
      for (int r=0;r<4;++r){
        cr[mf][nf][r] = accRR[mf][nf][r] - accII[mf][nf][r];
        ci[mf][nf][r] = accRI[mf][nf][r] + accIR[mf][nf][r];
      }

  // RoPE: head = this 64-col block; d = wc*16 + nfi*32 + l15, pair (d, d+32) = (nf0, nf1)
  const bool doRope = ROPE && (!SPLIT3 || (n0 < 2048));
  if (doRope){
    const float invf = powf(10000.0f, -(float)(wc*16 + l15) * (1.0f/32.0f));
    #pragma unroll
    for (int mf=0; mf<2; ++mf)
      #pragma unroll
      for (int r=0;r<4;++r){
        const int gm = m0 + wr*32 + mf*16 + quad*4 + r;
        float s, c;
        sincosf((float)(gm & (Lq-1)) * invf, &s, &c);
        float xr_ = cr[mf][0][r], yr_ = cr[mf][1][r];
        cr[mf][0][r] = xr_*c - yr_*s;  cr[mf][1][r] = yr_*c + xr_*s;
        float xi_ = ci[mf][0][r], yi_ = ci[mf][1][r];
        ci[mf][0][r] = xi_*c - yi_*s;  ci[mf][1][r] = yi_*c + xi_*s;
      }
  }

  unsigned short *oR16 = nullptr, *oI16 = nullptr;
  float *oR32 = nullptr, *oI32 = nullptr;
  int ncol0, Nst;
  if (SPLIT3){
    const int aid = n0 >> 10;
    void* vr = (aid==0) ? Cr0 : ((aid==1) ? Cr1 : Cr2);
    void* vi = (aid==0) ? Ci0 : ((aid==1) ? Ci1 : Ci2);
    oR16 = (unsigned short*)vr; oI16 = (unsigned short*)vi;
    ncol0 = n0 & 1023; Nst = 1024;
  } else {
    oR16 = (unsigned short*)Cr0; oI16 = (unsigned short*)Ci0;
    oR32 = (float*)Cr0;          oI32 = (float*)Ci0;
    ncol0 = n0; Nst = Ndim;
  }

  #pragma unroll
  for (int nf=0; nf<2; ++nf){
    const int gn = n0 + wc*16 + nf*32 + l15;      // full-N index (bias/modb)
    const int cn = ncol0 + wc*16 + nf*32 + l15;   // output-array col
    float bR = 0.f, bI = 0.f, mb = 0.f;
    if (EPI >= 1){ bR = biasR[gn]; bI = biasI[gn]; }
    if (EPI == 2){ mb = modb[gn]; }
    #pragma unroll
    for (int mf=0; mf<2; ++mf)
      #pragma unroll
      for (int r=0;r<4;++r){
        const int gm = m0 + wr*32 + mf*16 + quad*4 + r;
        const size_t idx = (size_t)gm*Nst + cn;
        float vr_ = cr[mf][nf][r] + bR, vi_ = ci[mf][nf][r] + bI;
        if (EPI == 1 || EPI == 3){ vr_ += resR[idx]; vi_ += resI[idx]; }
        if (EPI == 2){
          float mag = sqrtf(vr_*vr_ + vi_*vi_);
          float safe = (mag > 0.f) ? mag : 1.0f;
          float act = fmaxf(mag + mb, 0.f);
          float sc = act / safe;
          vr_ *= sc; vi_ *= sc;
        }
        if (EPI == 0 || EPI == 2){
          oR16[idx] = f2us(vr_);
          oI16[idx] = f2us(vi_);
        } else {
          oR32[idx] = vr_;
          oI32[idx] = vi_;
        }
      }
  }
}

// ---------------- V transpose: V[b,l,h*64+d] -> VT[(b*16+h)*64+d][l] ----------------
__global__ __launch_bounds__(256) void vtrans_kernel(
    const unsigned short* __restrict__ Vr, const unsigned short* __restrict__ Vi,
    unsigned short* __restrict__ VTr, unsigned short* __restrict__ VTi)
{
  const int lt = blockIdx.x;      // 0..15 (L tile)
  const int bh = blockIdx.y;      // 0..31
  const int h = bh & (Hq-1), b = bh >> 4;
  const int t = threadIdx.x;
  __shared__ unsigned short sTr[64*65], sTi[64*65];

  const int row = t >> 2;          // l-local 0..63
  const int dc  = (t & 3) * 16;    // d chunk
  const size_t g = ((size_t)(b*Lq) + lt*64 + row)*Dq + h*HDq + dc;
  uint4 a0 = *(const uint4*)(Vr + g);
  uint4 a1 = *(const uint4*)(Vr + g + 8);
  uint4 b0 = *(const uint4*)(Vi + g);
  uint4 b1 = *(const uint4*)(Vi + g + 8);
  const unsigned short* pa0 = (const unsigned short*)&a0;
  const unsigned short* pa1 = (const unsigned short*)&a1;
  const unsigned short* pb0 = (const unsigned short*)&b0;
  const unsigned short* pb1 = (const unsigned short*)&b1;
  #pragma unroll
  for (int e=0;e<8;++e){
    sTr[(dc+e)*65 + row]   = pa0[e];
    sTr[(dc+8+e)*65 + row] = pa1[e];
    sTi[(dc+e)*65 + row]   = pb0[e];
    sTi[(dc+8+e)*65 + row] = pb1[e];
  }
  __syncthreads();
  const int d  = t >> 2;
  const int lcx = (t & 3) * 16;
  unsigned short bufr[16], bufi[16];
  #pragma unroll
  for (int e=0;e<16;++e){
    bufr[e] = sTr[d*65 + lcx + e];
    bufi[e] = sTi[d*65 + lcx + e];
  }
  const size_t og = ((size_t)bh*HDq + d)*Lq + lt*64 + lcx;
  *(uint4*)(VTr + og)     = *(const uint4*)&bufr[0];
  *(uint4*)(VTr + og + 8) = *(const uint4*)&bufr[8];
  *(uint4*)(VTi + og)     = *(const uint4*)&bufi[0];
  *(uint4*)(VTi + og + 8) = *(const uint4*)&bufi[8];
}

// ---------------- flash attention: 64x64 tiles, MFMA, online softmax ----------------
__device__ __forceinline__ int swz(int v){ return v ^ ((v >> 4) & 7); }

__global__ __launch_bounds__(256,2) void fattn_kernel(
    const unsigned short* __restrict__ Qr, const unsigned short* __restrict__ Qi,
    const unsigned short* __restrict__ Kr, const unsigned short* __restrict__ Ki,
    const unsigned short* __restrict__ VTr, const unsigned short* __restrict__ VTi,
    unsigned short* __restrict__ Or, unsigned short* __restrict__ Oi)
{
  const int qt = (int)(gridDim.x - 1 - blockIdx.x);   // big tiles dispatch first
  const int bh = blockIdx.y;
  const int h = bh & (Hq-1), b = bh >> 4;
  const int t = threadIdx.x;
  const int w = t >> 6, lane = t & 63;
  const int quad = lane >> 4, l15 = lane & 15;

  __shared__ __align__(16) unsigned short sKr[4096], sKi[4096], sVr[4096], sVi[4096];
  __shared__ __align__(16) unsigned short sP[64*72];

  const size_t qbase = ((size_t)(b*Lq) + qt*64 + w*16 + l15)*Dq + h*HDq;
  bf16x8 qr_lo = *(const bf16x8*)(Qr + qbase + quad*8);
  bf16x8 qr_hi = *(const bf16x8*)(Qr + qbase + 32 + quad*8);
  bf16x8 qi_lo = *(const bf16x8*)(Qi + qbase + quad*8);
  bf16x8 qi_hi = *(const bf16x8*)(Qi + qbase + 32 + quad*8);

  const floatx4 fzero = {0.f,0.f,0.f,0.f};
  floatx4 aOr[4], aOi[4];
  #pragma unroll
  for (int i=0;i<4;++i){ aOr[i]=fzero; aOi[i]=fzero; }
  float m_run[4] = {-1e30f,-1e30f,-1e30f,-1e30f};
  float l_run[4] = {0.f,0.f,0.f,0.f};

  const int srow = t >> 2;
  const int sns  = srow >> 4;
  const int sl15 = srow & 15;
  const int q8   = (t & 3) * 2;
  const int dstA = sns*1024 + swz(q8*16 + sl15)*8;
  const int dstB = sns*1024 + swz((q8+1)*16 + sl15)*8;

  const int rd0 = swz(quad*16 + l15)*8;
  const int rd1 = swz((4+quad)*16 + l15)*8;

  for (int kt = 0; kt <= qt; ++kt){
    const size_t kg = ((size_t)(b*Lq) + kt*64 + srow)*Dq + h*HDq + q8*8;
    uint4 ka = *(const uint4*)(Kr + kg);
    uint4 kb = *(const uint4*)(Kr + kg + 8);
    uint4 kc = *(const uint4*)(Ki + kg);
    uint4 kd = *(const uint4*)(Ki + kg + 8);
    const size_t vg = ((size_t)bh*HDq + srow)*Lq + kt*64 + q8*8;
    uint4 va = *(const uint4*)(VTr + vg);
    uint4 vb = *(const uint4*)(VTr + vg + 8);
    uint4 vc = *(const uint4*)(VTi + vg);
    uint4 vd = *(const uint4*)(VTi + vg + 8);
    __syncthreads();
    *(uint4*)&sKr[dstA] = ka;  *(uint4*)&sKr[dstB] = kb;
    *(uint4*)&sKi[dstA] = kc;  *(uint4*)&sKi[dstB] = kd;
    *(uint4*)&sVr[dstA] = va;  *(uint4*)&sVr[dstB] = vb;
    *(uint4*)&sVi[dstA] = vc;  *(uint4*)&sVi[dstB] = vd;
    __syncthreads();

    floatx4 sc[4];
    #pragma unroll
    for (int ns=0; ns<4; ++ns){
      floatx4 x = fzero;
      x = __builtin_amdgcn_mfma_f32_16x16x32_bf16(qr_lo, *(const bf16x8*)&sKr[ns*1024 + rd0], x, 0,0,0);
      x = __builtin_amdgcn_mfma_f32_16x16x32_bf16(qr_hi, *(const bf16x8*)&sKr[ns*1024 + rd1], x, 0,0,0);
      x = __builtin_amdgcn_mfma_f32_16x16x32_bf16(qi_lo, *(const bf16x8*)&sKi[ns*1024 + rd0], x, 0,0,0);
      x = __builtin_amdgcn_mfma_f32_16x16x32_bf16(qi_hi, *(const bf16x8*)&sKi[ns*1024 + rd1], x, 0,0,0);
      sc[ns] = x;
    }

    const bool diag = (kt == qt);
    float rmax[4] = {-1e30f,-1e30f,-1e30f,-1e30f};
    #pragma unroll
    for (int ns=0; ns<4; ++ns){
      #pragma unroll
      for (int r=0; r<4; ++r){
        float s = sc[ns][r] * 0.125f;
        if (diag && (ns*16 + l15 > w*16 + quad*4 + r)) s = -1e30f;
        sc[ns][r] = s;
        rmax[r] = fmaxf(rmax[r], s);
      }
    }
    #pragma unroll
    for (int off=1; off<16; off<<=1){
      #pragma unroll
      for (int r=0; r<4; ++r) rmax[r] = fmaxf(rmax[r], __shfl_xor(rmax[r], off, 64));
    }

    float alpha[4], rsum[4];
    #pragma unroll
    for (int r=0; r<4; ++r){
      float mn = fmaxf(m_run[r], rmax[r]);
      alpha[r] = __expf(m_run[r] - mn);
      m_run[r] = mn;
      rsum[r] = 0.f;
    }
    #pragma unroll
    for (int ns=0; ns<4; ++ns){
      #pragma unroll
      for (int r=0; r<4; ++r){
        float p = __expf(sc[ns][r] - m_run[r]);
        rsum[r] += p;
        sP[(w*16 + quad*4 + r)*72 + ns*16 + l15] = f2us(p);
      }
    }
    #pragma unroll
    for (int off=1; off<16; off<<=1){
      #pragma unroll
      for (int r=0; r<4; ++r) rsum[r] += __shfl_xor(rsum[r], off, 64);
    }
    #pragma unroll
    for (int r=0; r<4; ++r) l_run[r] = l_run[r]*alpha[r] + rsum[r];
    #pragma unroll
    for (int ds=0; ds<4; ++ds)
      #pragma unroll
      for (int r=0; r<4; ++r){ aOr[ds][r] *= alpha[r]; aOi[ds][r] *= alpha[r]; }

    #pragma unroll
    for (int step=0; step<2; ++step){
      bf16x8 pf = *(const bf16x8*)&sP[(w*16 + l15)*72 + step*32 + quad*8];
      const int ro = (step==0) ? rd0 : rd1;
      #pragma unroll
      for (int ds=0; ds<4; ++ds){
        aOr[ds] = __builtin_amdgcn_mfma_f32_16x16x32_bf16(pf, *(const bf16x8*)&sVr[ds*1024 + ro], aOr[ds], 0,0,0);
        aOi[ds] = __builtin_amdgcn_mfma_f32_16x16x32_bf16(pf, *(const bf16x8*)&sVi[ds*1024 + ro], aOi[ds], 0,0,0);
      }
    }
  }

  #pragma unroll
  for (int r=0; r<4; ++r){
    const float il = 1.0f / l_run[r];
    const size_t ob = ((size_t)(b*Lq) + qt*64 + w*16 + quad*4 + r)*Dq + h*HDq;
    #pragma unroll
    for (int ds=0; ds<4; ++ds){
      Or[ob + ds*16 + l15] = f2us(aOr[ds][r] * il);
      Oi[ob + ds*16 + l15] = f2us(aOi[ds][r] * il);
    }
  }
}

// ---------------- launch ----------------
extern "C" void kernel_launch(void* const* d_in, const int* in_sizes, int n_in,
                              void* d_out, int out_size, void* d_ws, size_t ws_size,
                              hipStream_t stream)
{
  const float* x_r    = (const float*)d_in[0];
  const float* x_i    = (const float*)d_in[1];
  const float* Wq_r   = (const float*)d_in[2];
  const float* Wq_i   = (const float*)d_in[3];
  const float* Wk_r   = (const float*)d_in[4];
  const float* Wk_i   = (const float*)d_in[5];
  const float* Wv_r   = (const float*)d_in[6];
  const float* Wv_i   = (const float*)d_in[7];
  const float* Wo_r   = (const float*)d_in[8];
  const float* Wo_i   = (const float*)d_in[9];
  const float* bo_r   = (const float*)d_in[10];
  const float* bo_i   = (const float*)d_in[11];
  const float* ln1_gr = (const float*)d_in[12];
  const float* ln1_gi = (const float*)d_in[13];
  const float* ln1_br = (const float*)d_in[14];
  const float* ln1_bi = (const float*)d_in[15];
  const float* ln2_gr = (const float*)d_in[16];
  const float* ln2_gi = (const float*)d_in[17];
  const float* ln2_br = (const float*)d_in[18];
  const float* ln2_bi = (const float*)d_in[19];
  const float* W1_r   = (const float*)d_in[20];
  const float* W1_i   = (const float*)d_in[21];
  const float* b1_r   = (const float*)d_in[22];
  const float* b1_i   = (const float*)d_in[23];
  const float* W2_r   = (const float*)d_in[24];
  const float* W2_i   = (const float*)d_in[25];
  const float* b2_r   = (const float*)d_in[26];
  const float* b2_i   = (const float*)d_in[27];
  const float* mod_b  = (const float*)d_in[28];

  char* wsb = (char*)d_ws;
  const size_t MB = 1024*1024;
  // --- weights, bf16: 0..48 MB ---
  // QKV weights stacked [3072][1024] for the merged projection GEMM
  unsigned short* bQKV_r = (unsigned short*)(wsb + 0*MB);   // Wq_r @0, Wk_r @2MB, Wv_r @4MB
  unsigned short* bQKV_i = (unsigned short*)(wsb + 6*MB);   // Wq_i @6, Wk_i @8, Wv_i @10
  unsigned short* bWo_r = (unsigned short*)(wsb + 12*MB);
  unsigned short* bWo_i = (unsigned short*)(wsb + 14*MB);
  unsigned short* bW1_r = (unsigned short*)(wsb + 16*MB);
  unsigned short* bW1_i = (unsigned short*)(wsb + 24*MB);
  unsigned short* bW2_r = (unsigned short*)(wsb + 32*MB);
  unsigned short* bW2_i = (unsigned short*)(wsb + 40*MB);
  // --- activations: 48..96 MB ---
  unsigned short* hr  = (unsigned short*)(wsb + 48*MB);
  unsigned short* hi_ = (unsigned short*)(wsb + 52*MB);
  unsigned short* Qr  = (unsigned short*)(wsb + 56*MB);
  unsigned short* Qi  = (unsigned short*)(wsb + 60*MB);
  unsigned short* Kr  = (unsigned short*)(wsb + 64*MB);
  unsigned short* Ki  = (unsigned short*)(wsb + 68*MB);
  unsigned short* Vr  = (unsigned short*)(wsb + 72*MB);
  unsigned short* Vi  = (unsigned short*)(wsb + 76*MB);
  unsigned short* VTr = (unsigned short*)(wsb + 80*MB);
  unsigned short* VTi = (unsigned short*)(wsb + 84*MB);
  unsigned short* Or  = hr;                               // hr/hi dead after QKV gemm
  unsigned short* Oi  = hi_;
  unsigned short* h2r = Qr;                               // Q dead after attn
  unsigned short* h2i = Qi;
  unsigned short* fr  = (unsigned short*)(wsb + 64*MB);   // over K/V (dead after attn)
  unsigned short* fi  = (unsigned short*)(wsb + 80*MB);   // over VT (dead after attn)

  float* outR = (float*)d_out;
  float* outI = outR + (size_t)Mq*Dq;

  const dim3 blk(256);

  const int nDD = Dq*Dq;
  const int nDH = Dq*HIDq;
  cvt4_kernel<<<dim3(nDD/2048, 4), blk, 0, stream>>>(Wq_r, Wk_r, Wv_r, Wo_r,
      bQKV_r, bQKV_r + (size_t)nDD, bQKV_r + (size_t)2*nDD, bWo_r, nDD);
  cvt4_kernel<<<dim3(nDD/2048, 4), blk, 0, stream>>>(Wq_i, Wk_i, Wv_i, Wo_i,
      bQKV_i, bQKV_i + (size_t)nDD, bQKV_i + (size_t)2*nDD, bWo_i, nDD);
  cvt4_kernel<<<dim3(nDH/2048, 4), blk, 0, stream>>>(W1_r, W1_i, W2_r, W2_i,
      bW1_r, bW1_i, bW2_r, bW2_i, nDH);

  // 1. ln1
  cln_kernel<<<Mq, blk, 0, stream>>>(x_r, x_i, ln1_gr, ln1_gi, ln1_br, ln1_bi, hr, hi_);
  // 2. merged Q,K,V projection (RoPE fused on Q,K; scatter to 3 arrays)
  cgemm16_kernel<0,true,true><<<dim3(Mq/64, 3072/64), blk, 0, stream>>>(
      hr, hi_, bQKV_r, bQKV_i,
      Qr, Qi, Kr, Ki, Vr, Vi,
      nullptr, nullptr, nullptr, nullptr, nullptr, 3072, Dq);
  // 2b. V transpose for PV fragments
  vtrans_kernel<<<dim3(16, 32), blk, 0, stream>>>(Vr, Vi, VTr, VTi);
  // 3. flash attention (writes O over hr/hi)
  fattn_kernel<<<dim3(16, 32), blk, 0, stream>>>(Qr, Qi, Kr, Ki, VTr, VTi, Or, Oi);
  // 4. Wo + bias + residual(x) -> d_out (f32)
  cgemm16_kernel<1,false,false><<<dim3(Mq/64, Dq/64), blk, 0, stream>>>(
      Or, Oi, bWo_r, bWo_i, outR, outI, nullptr, nullptr, nullptr, nullptr,
      bo_r, bo_i, x_r, x_i, nullptr, Dq, Dq);
  // 5. ln2
  cln_kernel<<<Mq, blk, 0, stream>>>(outR, outI, ln2_gr, ln2_gi, ln2_br, ln2_bi, h2r, h2i);
  // 6. W1 + bias + ModReLU -> f
  cgemm16_kernel<2,false,false><<<dim3(Mq/64, HIDq/64), blk, 0, stream>>>(
      h2r, h2i, bW1_r, bW1_i, fr, fi, nullptr, nullptr, nullptr, nullptr,
      b1_r, b1_i, nullptr, nullptr, mod_b, HIDq, Dq);
  // 7. W2 + bias + residual(d_out) -> d_out in-place (f32)
  cgemm16_kernel<3,false,false><<<dim3(Mq/64, Dq/64), blk, 0, stream>>>(
      fr, fi, bW2_r, bW2_i, outR, outI, nullptr, nullptr, nullptr, nullptr,
      b2_r, b2_i, outR, outI, nullptr, Dq, HIDq);
}